// Round 12
// baseline (4326.913 us; speedup 1.0000x reference)
//
#include <hip/hip_runtime.h>
#include <hip/hip_bf16.h>

// Problem constants (match reference)
constexpr int Bc   = 2;
constexpr int Tc   = 1024;
constexpr int Vc   = 50257;
constexpr int Lc   = 8;
constexpr int Dc   = 1024;
constexpr int Hc   = 16;
constexpr int HKVc = 4;
constexpr int HDc  = 64;     // D/H
constexpr int KVDc = 256;    // HKV*HD
constexpr int MLPc = 4096;   // 4*D
constexpr int BVc  = 65536;
constexpr int BDc  = 256;
constexpr int VEDc = 128;

constexpr int NTOK = Bc * Tc;          // 2048
constexpr long SZ_X  = (long)NTOK * Dc;    // 2,097,152
constexpr long SZ_KV = (long)NTOK * KVDc;  // 524,288
constexpr long SZ_H  = (long)NTOK * MLPc;  // 8,388,608

constexpr int  VPAD = 50432;                  // Vc padded to 256
constexpr long W_Q  = (long)Lc * Dc * Dc;     // 8,388,608
constexpr long W_KV = (long)Lc * KVDc * Dc;   // 2,097,152
constexpr long W_FC = (long)Lc * MLPc * Dc;   // 33,554,432
constexpr long W_HD = (long)VPAD * Dc;        // frag-order, padded
constexpr long SZ_KVP = (long)Bc * HKVc * (Tc / 64) * 4096;  // shorts/plane

#define NEG_BIG (-3.0e38f)

typedef __attribute__((ext_vector_type(8))) short short8;    // 8 bf16 (4 VGPRs)
typedef __attribute__((ext_vector_type(4))) short short4v;   // 4 bf16 (8 B)
typedef __attribute__((ext_vector_type(4))) float floatx4;   // 16x16 MFMA acc
typedef __attribute__((ext_vector_type(16))) float floatx16; // 32x32 MFMA acc

__device__ __forceinline__ float wave_sum(float v) {
#pragma unroll
  for (int off = 32; off >= 1; off >>= 1) v += __shfl_xor(v, off);
  return v;
}

// Bijective XCD-aware swizzle (m204 formula).
__device__ __forceinline__ void xcd_swizzle(int& bx, int& by, int nbx, int nby) {
  int n = nbx * nby;
  int lin = by * nbx + bx;
  int q = n >> 3, rm = n & 7;
  int xcd = lin & 7, idx = lin >> 3;
  int v = (xcd < rm) ? (xcd * (q + 1) + idx)
                     : (rm * (q + 1) + (xcd - rm) * q + idx);
  bx = v % nbx;
  by = v / nbx;
}

// async global->LDS, 16B per lane. LDS dest = wave-uniform base + lane*16.
__device__ __forceinline__ void gll16(const void* g, void* l) {
  __builtin_amdgcn_global_load_lds(
      (const __attribute__((address_space(1))) unsigned int*)g,
      (__attribute__((address_space(3))) unsigned int*)l, 16, 0, 0);
}

// ---------------------------------------------------------------------------
// bf16 split helpers: f = bf2f(hi) + bf2f(lo) + O(2^-17 * f)
// ---------------------------------------------------------------------------
__device__ __forceinline__ short f2bf(float f) {
  unsigned u = __float_as_uint(f);
  return (short)((u + 0x7fffu + ((u >> 16) & 1u)) >> 16);
}
__device__ __forceinline__ float bf2f(short h) {
  return __uint_as_float(((unsigned)(unsigned short)h) << 16);
}

// ---------------------------------------------------------------------------
// Weight conversion: fp32 row-major [N][K] -> frag-order hi/lo planes
//   layout [Npad/32][K/16][64 lanes][8 shorts]; lane = (r&31) + 32*(k8&1).
// Layer-contiguous: batched over all layers in ONE launch.
// ---------------------------------------------------------------------------
__global__ __launch_bounds__(256) void wcvt_frag_kernel(
    const float* __restrict__ src, short* __restrict__ hi,
    short* __restrict__ lo, int N, int Npad, int K) {
  long i = (long)blockIdx.x * 256 + threadIdx.x;
  int K8 = K >> 3;
  long n8 = (long)Npad * K8;
  if (i >= n8) return;
  int r = (int)(i / K8);
  int k8 = (int)(i % K8);
  float fv[8] = {};
  if (r < N) {
    const float* s = src + (size_t)r * K + k8 * 8;
    float4 f0 = *(const float4*)s;
    float4 f1 = *(const float4*)(s + 4);
    fv[0] = f0.x; fv[1] = f0.y; fv[2] = f0.z; fv[3] = f0.w;
    fv[4] = f1.x; fv[5] = f1.y; fv[6] = f1.z; fv[7] = f1.w;
  }
  short8 h8, l8;
#pragma unroll
  for (int e = 0; e < 8; ++e) {
    short hb = f2bf(fv[e]);
    h8[e] = hb;
    l8[e] = f2bf(fv[e] - bf2f(hb));
  }
  int rg = r >> 5, ksi = k8 >> 1;
  int lanev = (r & 31) + ((k8 & 1) << 5);
  size_t off = (((size_t)rg * (K >> 4) + ksi) * 64 + lanev) * 8;
  *(short8*)(hi + off) = h8;
  *(short8*)(lo + off) = l8;
}

// ---------------------------------------------------------------------------
// Embedding (unchanged)
// ---------------------------------------------------------------------------
__global__ __launch_bounds__(256) void embed_kernel(
    const int* __restrict__ ids, const float* __restrict__ embed_w,
    const float* __restrict__ big_w, const float* __restrict__ big_proj,
    const float* __restrict__ big_scale, const float* __restrict__ ve_w,
    const float* __restrict__ ve_proj, const float* __restrict__ ve_scale,
    float* __restrict__ raw_x, float* __restrict__ vemb) {
  int bt = blockIdx.x;
  int tid = threadIdx.x;
  int t = bt % Tc;
  int tok = ids[bt];

  const float* e = embed_w + (size_t)tok * Dc;
  float ev[4];
  float ss = 0.f;
#pragma unroll
  for (int i = 0; i < 4; ++i) {
    ev[i] = e[tid + i * 256];
    ss += ev[i] * ev[i];
  }
  __shared__ float red[4];
  __shared__ float brow[BDc];
  __shared__ float verow[VEDc];
  float wsum = wave_sum(ss);
  if ((tid & 63) == 0) red[tid >> 6] = wsum;

  int bg;
  if (t == 0) {
    bg = BVc - 1;
  } else {
    unsigned a = (unsigned)ids[bt];
    unsigned p = (unsigned)ids[bt - 1];
    bg = (int)(((36313u * a) ^ (27191u * p)) % 65535u);
  }
  brow[tid] = big_w[(size_t)bg * BDc + tid];
  if (tid < VEDc) verow[tid] = ve_w[(size_t)tok * VEDc + tid];
  __syncthreads();

  float tot = red[0] + red[1] + red[2] + red[3];
  float rn = rsqrtf(tot / (float)Dc + 1e-6f);
  float bs = big_scale[0];
#pragma unroll
  for (int i = 0; i < 4; ++i) {
    int d = tid + i * 256;
    const float* bp = big_proj + (size_t)d * BDc;
    float dot = 0.f;
    for (int c = 0; c < BDc; ++c) dot += brow[c] * bp[c];
    raw_x[(size_t)bt * Dc + d] = ev[i] * rn + dot * bs;
  }
  {
    float vs = ve_scale[0];
    int d = tid;
    const float* vp = ve_proj + (size_t)d * VEDc;
    float dot = 0.f;
    for (int c = 0; c < VEDc; ++c) dot += verow[c] * vp[c];
    vemb[(size_t)bt * KVDc + d] = dot * vs;
  }
}

// ---------------------------------------------------------------------------
// Smear (unchanged)
// ---------------------------------------------------------------------------
__global__ __launch_bounds__(256) void smear_kernel(
    const float* __restrict__ raw, const float* __restrict__ gate,
    float* __restrict__ x, float* __restrict__ x0) {
  long idx = (long)blockIdx.x * 256 + threadIdx.x;
  if (idx >= SZ_X) return;
  int d = (int)(idx & (Dc - 1));
  int t = (int)((idx / Dc) & (Tc - 1));
  float g = 1.f / (1.f + expf(-gate[d]));
  float cur = raw[idx];
  float prev = (t > 0) ? raw[idx - Dc] : 0.f;
  float val = (1.f - g) * cur + g * prev;
  x[idx] = val;
  x0[idx] = val;
}

// ---------------------------------------------------------------------------
// frag-order activation store: token bt, 4 consecutive elems at d0=4*tid.
// ---------------------------------------------------------------------------
__device__ __forceinline__ void store_frag4(short* __restrict__ ph,
                                            short* __restrict__ pl, int bt,
                                            int d0, int K16, const float* v) {
  short4v h4, l4;
#pragma unroll
  for (int e = 0; e < 4; ++e) {
    short hb = f2bf(v[e]);
    h4[e] = hb;
    l4[e] = f2bf(v[e] - bf2f(hb));
  }
  int lanev = (bt & 31) + 32 * ((d0 >> 3) & 1);
  size_t off = (((size_t)(bt >> 5) * K16 + (d0 >> 4)) * 64 + lanev) * 8 + (d0 & 7);
  *(short4v*)(ph + off) = h4;
  *(short4v*)(pl + off) = l4;
}

// ---------------------------------------------------------------------------
// Pre-layer: x_in = mix0*x + mix1*x0 ; xn frag planes = split(rms(x_in)).
// ---------------------------------------------------------------------------
__global__ __launch_bounds__(256) void prelayer_kernel(
    const float* __restrict__ x, const float* __restrict__ x0,
    const float* __restrict__ mix, float* __restrict__ x_in,
    short* __restrict__ xnh, short* __restrict__ xnl) {
  int bt = blockIdx.x;
  int tid = threadIdx.x;
  int d0 = tid * 4;
  const float* xr = x + (size_t)bt * Dc;
  const float* x0r = x0 + (size_t)bt * Dc;
  float4 xv = *(const float4*)(xr + d0);
  float4 x0v = *(const float4*)(x0r + d0);
  float4 m0 = *(const float4*)(mix + d0);
  float4 m1 = *(const float4*)(mix + Dc + d0);
  float vals[4] = {m0.x * xv.x + m1.x * x0v.x, m0.y * xv.y + m1.y * x0v.y,
                   m0.z * xv.z + m1.z * x0v.z, m0.w * xv.w + m1.w * x0v.w};
  float ss = vals[0] * vals[0] + vals[1] * vals[1] + vals[2] * vals[2] +
             vals[3] * vals[3];
  __shared__ float red[4];
  float wsum = wave_sum(ss);
  if ((tid & 63) == 0) red[tid >> 6] = wsum;
  __syncthreads();
  float tot = red[0] + red[1] + red[2] + red[3];
  float rn = rsqrtf(tot / (float)Dc + 1e-6f);
  *(float4*)(x_in + (size_t)bt * Dc + d0) =
      make_float4(vals[0], vals[1], vals[2], vals[3]);
  float vn[4] = {vals[0] * rn, vals[1] * rn, vals[2] * rn, vals[3] * rn};
  store_frag4(xnh, xnl, bt, d0, Dc >> 4, vn);
}

// ---------------------------------------------------------------------------
// RMS over D -> frag-order bf16 hi/lo planes. Block per token.
// ---------------------------------------------------------------------------
__global__ __launch_bounds__(256) void rms_split_kernel(
    const float* __restrict__ in, short* __restrict__ oh,
    short* __restrict__ ol) {
  int bt = blockIdx.x;
  int tid = threadIdx.x;
  int d0 = tid * 4;
  float4 v4 = *(const float4*)(in + (size_t)bt * Dc + d0);
  float v[4] = {v4.x, v4.y, v4.z, v4.w};
  float ss = v[0] * v[0] + v[1] * v[1] + v[2] * v[2] + v[3] * v[3];
  __shared__ float red[4];
  float wsum = wave_sum(ss);
  if ((tid & 63) == 0) red[tid >> 6] = wsum;
  __syncthreads();
  float tot = red[0] + red[1] + red[2] + red[3];
  float rn = rsqrtf(tot / (float)Dc + 1e-6f);
  float vn[4] = {v[0] * rn, v[1] * rn, v[2] * rn, v[3] * rn};
  store_frag4(oh, ol, bt, d0, Dc >> 4, vn);
}

// ---------------------------------------------------------------------------
// Frag-order GEMM core (R9 structure; counted-vmcnt dbuf pipeline).
// Both operands in frag-order planes [R/32][K/16][64][8]; 1KB packets.
// BM=128/BN=256 variant cuts LDS bytes per FLOP (port cap 51% -> ~68%).
// ---------------------------------------------------------------------------
template <int BM, int BN>
__device__ __forceinline__ void gemm_frag_core(
    const short* __restrict__ Afh, const short* __restrict__ Afl,
    const short* __restrict__ Bfh, const short* __restrict__ Bfl, int m0,
    int n0, int K, short* lds, floatx16 (*acc)[BN / 64]) {
  constexpr int RGA = BM / 32;
  constexpr int RGB = BN / 32;
  constexpr int SPW = RGA + RGB;        // gll16 per wave per tile
  constexpr int PLA = RGA * 1024;
  constexpr int PLB = RGB * 1024;
  constexpr int HB = 2 * (PLA + PLB);   // shorts per buffer
  constexpr int FI = BM / 64;
  constexpr int FJ = BN / 64;
  static_assert(SPW == 6 || SPW == 12, "unexpected tile config");

  int tid = threadIdx.x, lane = tid & 63, wv = tid >> 6;
  int K16 = K >> 4;

  const short* gsrc[SPW];
  int ldst[SPW];
#pragma unroll
  for (int t = 0; t < SPW; ++t) {
    int s = wv * SPW + t;
    const short* plane;
    int poff, rg, ks;
    size_t base;
    if (s < RGA * 4) {
      int p = s / (RGA * 2);
      int rem = s % (RGA * 2);
      rg = rem >> 1; ks = rem & 1;
      plane = p ? Afl : Afh;
      poff = p ? PLA : 0;
      base = (((size_t)(m0 >> 5) + rg) * K16 + ks) * 512;
    } else {
      int s2 = s - RGA * 4;
      int p = s2 / (RGB * 2);
      int rem = s2 % (RGB * 2);
      rg = rem >> 1; ks = rem & 1;
      plane = p ? Bfl : Bfh;
      poff = 2 * PLA + (p ? PLB : 0);
      base = (((size_t)(n0 >> 5) + rg) * K16 + ks) * 512;
    }
    gsrc[t] = plane + base + lane * 8;
    ldst[t] = poff + (rg * 2 + ks) * 512;
  }

  int wm = (wv >> 1) * (BM / 2), wn = (wv & 1) * (BN / 2);

  // prologue: tile 0 -> buf0, tile 1 -> buf1 (K >= 64 everywhere here)
#pragma unroll
  for (int t = 0; t < SPW; ++t) gll16(gsrc[t], lds + ldst[t]);
#pragma unroll
  for (int t = 0; t < SPW; ++t) gsrc[t] += 1024;
#pragma unroll
  for (int t = 0; t < SPW; ++t) gll16(gsrc[t], lds + HB + ldst[t]);
#pragma unroll
  for (int t = 0; t < SPW; ++t) gsrc[t] += 1024;

  int cur = 0;
  for (int k0 = 0; k0 < K; k0 += 32) {
    if (k0 + 32 < K) {
      if constexpr (SPW == 12) {
        asm volatile("s_waitcnt vmcnt(12)" ::: "memory");
      } else {
        asm volatile("s_waitcnt vmcnt(6)" ::: "memory");
      }
    } else {
      asm volatile("s_waitcnt vmcnt(0)" ::: "memory");
    }
    __builtin_amdgcn_s_barrier();
    __builtin_amdgcn_sched_barrier(0);

    const short* As_h = lds + cur * HB;
    const short* As_l = As_h + PLA;
    const short* Bs_h = As_h + 2 * PLA;
    const short* Bs_l = Bs_h + PLB;
    short8 ah[2][FI], alx[2][FI], bhx[2][FJ], blx[2][FJ];
#pragma unroll
    for (int ks = 0; ks < 2; ++ks) {
#pragma unroll
      for (int i = 0; i < FI; ++i) {
        int rg = (wm >> 5) + i;
        ah[ks][i]  = *(const short8*)(As_h + (rg * 2 + ks) * 512 + lane * 8);
        alx[ks][i] = *(const short8*)(As_l + (rg * 2 + ks) * 512 + lane * 8);
      }
#pragma unroll
      for (int j = 0; j < FJ; ++j) {
        int rg = (wn >> 5) + j;
        bhx[ks][j] = *(const short8*)(Bs_h + (rg * 2 + ks) * 512 + lane * 8);
        blx[ks][j] = *(const short8*)(Bs_l + (rg * 2 + ks) * 512 + lane * 8);
      }
    }
    asm volatile("s_waitcnt lgkmcnt(0)" ::: "memory");
    __builtin_amdgcn_sched_barrier(0);
    __builtin_amdgcn_s_barrier();  // all waves done reading buf[cur]

    if (k0 + 64 < K) {  // stage tile k+2 into freed buffer
#pragma unroll
      for (int t = 0; t < SPW; ++t) gll16(gsrc[t], lds + cur * HB + ldst[t]);
#pragma unroll
      for (int t = 0; t < SPW; ++t) gsrc[t] += 1024;
    }
    __builtin_amdgcn_sched_barrier(0);

    __builtin_amdgcn_s_setprio(1);
#pragma unroll
    for (int ks = 0; ks < 2; ++ks) {
#pragma unroll
      for (int i = 0; i < FI; ++i)
#pragma unroll
        for (int j = 0; j < FJ; ++j)
          acc[i][j] = __builtin_amdgcn_mfma_f32_32x32x16_bf16(ah[ks][i], bhx[ks][j], acc[i][j], 0, 0, 0);
#pragma unroll
      for (int i = 0; i < FI; ++i)
#pragma unroll
        for (int j = 0; j < FJ; ++j)
          acc[i][j] = __builtin_amdgcn_mfma_f32_32x32x16_bf16(ah[ks][i], blx[ks][j], acc[i][j], 0, 0, 0);
#pragma unroll
      for (int i = 0; i < FI; ++i)
#pragma unroll
        for (int j = 0; j < FJ; ++j)
          acc[i][j] = __builtin_amdgcn_mfma_f32_32x32x16_bf16(alx[ks][i], bhx[ks][j], acc[i][j], 0, 0, 0);
    }
    __builtin_amdgcn_s_setprio(0);
    cur ^= 1;
  }
}

// head GEMM: 128x256 tile (FJ=4, port cap ~68%), fp32 C with column guard.
__global__ __launch_bounds__(256, 1) void head_frag(
    const short* __restrict__ Afh, const short* __restrict__ Afl,
    const short* __restrict__ Bfh, const short* __restrict__ Bfl,
    float* __restrict__ C, int N, int K) {
  __shared__ short lds[49152];  // 96 KiB (2 buffers x 48 KB)
  int bx = blockIdx.x, by = blockIdx.y;
  xcd_swizzle(bx, by, gridDim.x, gridDim.y);
  int m0 = bx * 128, n0 = by * 256;
  floatx16 acc[2][4] = {};
  gemm_frag_core<128, 256>(Afh, Afl, Bfh, Bfl, m0, n0, K, lds, acc);
  int lane = threadIdx.x & 63, wv = threadIdx.x >> 6;
  int wm = (wv >> 1) * 64, wn = (wv & 1) * 128;
  int cl = lane & 31, g2 = lane >> 5;
#pragma unroll
  for (int i = 0; i < 2; ++i)
#pragma unroll
    for (int j = 0; j < 4; ++j) {
      int col = n0 + wn + 32 * j + cl;
      if (col >= N) continue;
      floatx16 f = acc[i][j];
#pragma unroll
      for (int r = 0; r < 16; ++r) {
        int row = m0 + wm + 32 * i + (r & 3) + 8 * (r >> 2) + 4 * g2;
        C[(size_t)row * N + col] = f[r];
      }
    }
}

// Wp GEMM: 64x128, fp32 C = base + colscale * acc. (Wo, Wp)
__global__ __launch_bounds__(256, 3) void wp_frag(
    const short* __restrict__ Afh, const short* __restrict__ Afl,
    const short* __restrict__ Bfh, const short* __restrict__ Bfl,
    float* __restrict__ C, const float* __restrict__ base,
    const float* __restrict__ colscale, int N, int K) {
  __shared__ short lds[24576];  // 48 KiB
  int bx = blockIdx.x, by = blockIdx.y;
  xcd_swizzle(bx, by, gridDim.x, gridDim.y);
  int m0 = bx * 64, n0 = by * 128;
  floatx16 acc[1][2] = {};
  gemm_frag_core<64, 128>(Afh, Afl, Bfh, Bfl, m0, n0, K, lds, acc);
  int lane = threadIdx.x & 63, wv = threadIdx.x >> 6;
  int wm = (wv >> 1) * 32, wn = (wv & 1) * 64;
  int cl = lane & 31, g2 = lane >> 5;
#pragma unroll
  for (int j = 0; j < 2; ++j) {
    int col = n0 + wn + 32 * j + cl;
    floatx16 f = acc[0][j];
    float cs = colscale ? colscale[col] : 1.f;
#pragma unroll
    for (int r = 0; r < 16; ++r) {
      int row = m0 + wm + (r & 3) + 8 * (r >> 2) + 4 * g2;
      size_t idx = (size_t)row * N + col;
      float v = f[r] * cs;
      if (base) v += base[idx];
      C[idx] = v;
    }
  }
}

// Fused q,k,v: grid (NTOK/64, 12). by<8 -> q, 8-9 -> k, 10-11 -> v (+vemb).
__global__ __launch_bounds__(256, 3) void qkv_frag(
    const short* __restrict__ xnh, const short* __restrict__ xnl,
    const short* __restrict__ wqh, const short* __restrict__ wql,
    const short* __restrict__ wkh, const short* __restrict__ wkl,
    const short* __restrict__ wvh, const short* __restrict__ wvl,
    float* __restrict__ qb, float* __restrict__ kb, float* __restrict__ vb,
    const float* __restrict__ vemb, int K) {
  __shared__ short lds[24576];  // 48 KiB
  int bx = blockIdx.x, by = blockIdx.y;
  xcd_swizzle(bx, by, gridDim.x, gridDim.y);
  const short *Bh, *Bl;
  float* C;
  const float* base = nullptr;
  int n0, ldn;
  if (by < 8) {
    Bh = wqh; Bl = wql; C = qb; n0 = by * 128; ldn = Dc;
  } else if (by < 10) {
    Bh = wkh; Bl = wkl; C = kb; n0 = (by - 8) * 128; ldn = KVDc;
  } else {
    Bh = wvh; Bl = wvl; C = vb; base = vemb; n0 = (by - 10) * 128; ldn = KVDc;
  }
  int m0 = bx * 64;
  floatx16 acc[1][2] = {};
  gemm_frag_core<64, 128>(xnh, xnl, Bh, Bl, m0, n0, K, lds, acc);
  int lane = threadIdx.x & 63, wv = threadIdx.x >> 6;
  int wm = (wv >> 1) * 32, wn = (wv & 1) * 64;
  int cl = lane & 31, g2 = lane >> 5;
#pragma unroll
  for (int j = 0; j < 2; ++j) {
    int col = n0 + wn + 32 * j + cl;
    floatx16 f = acc[0][j];
#pragma unroll
    for (int r = 0; r < 16; ++r) {
      int row = m0 + wm + (r & 3) + 8 * (r >> 2) + 4 * g2;
      size_t idx = (size_t)row * ldn + col;
      float v = f[r];
      if (base) v += base[idx];
      C[idx] = v;
    }
  }
}

// Wfc GEMM: 128x256 tile, act=1, writes h in FRAG-ORDER planes.
// Epilogue bounce one plane at a time (64 KB fits the 96 KB LDS).
__global__ __launch_bounds__(256, 1) void fc_frag(
    const short* __restrict__ Afh, const short* __restrict__ Afl,
    const short* __restrict__ Bfh, const short* __restrict__ Bfl,
    short* __restrict__ Chf, short* __restrict__ Clf, int N, int K,
    int K16out) {
  __shared__ short lds[49152];  // 96 KiB
  int bx = blockIdx.x, by = blockIdx.y;
  xcd_swizzle(bx, by, gridDim.x, gridDim.y);
  int m0 = bx * 128, n0 = by * 256;
  floatx16 acc[2][4] = {};
  gemm_frag_core<128, 256>(Afh, Afl, Bfh, Bfl, m0, n0, K, lds, acc);
  int tid = threadIdx.x;
  int lane = tid & 63, wv = tid >> 6;
  int wm = (wv >> 1) * 64, wn = (wv & 1) * 128;
  int cl = lane & 31, g2 = lane >> 5;
  __syncthreads();  // LDS free; plane-at-a-time frag bounce
  for (int pl = 0; pl < 2; ++pl) {
#pragma unroll
    for (int i = 0; i < 2; ++i)
#pragma unroll
      for (int j = 0; j < 4; ++j) {
        floatx16 f = acc[i][j];
#pragma unroll
        for (int r = 0; r < 16; ++r) {
          int rowl = wm + 32 * i + (r & 3) + 8 * (r >> 2) + 4 * g2;  // 0..127
          int coll = wn + 32 * j + cl;                                // 0..255
          float v = f[r];
          float hx = (v >= 0.f) ? v : 0.5f * v;
          v = hx * hx;
          short hb = f2bf(v);
          short val = pl ? f2bf(v - bf2f(hb)) : hb;
          int sub = (rowl >> 5) * 16 + (coll >> 4);
          int lanev = (rowl & 31) + 32 * ((coll >> 3) & 1);
          lds[sub * 512 + lanev * 8 + (coll & 7)] = val;
        }
      }
    __syncthreads();
    short* dst = pl ? Clf : Chf;
    size_t gbase = ((size_t)(m0 >> 5) * K16out + (n0 >> 4)) * 512;
#pragma unroll
    for (int u = 0; u < 16; ++u) {
      int idx = u * 2048 + tid * 8;
      int sub = idx >> 9, within = idx & 511;
      size_t gidx =
          gbase + ((size_t)(sub >> 4) * K16out + (sub & 15)) * 512 + within;
      *(short8*)(dst + gidx) = *(const short8*)(lds + idx);
    }
    __syncthreads();
  }
}

// ---------------------------------------------------------------------------
// QK head-RMS + RoPE (+q_gain). Block per token. (unchanged)
// ---------------------------------------------------------------------------
__global__ __launch_bounds__(256) void qkrope_kernel(
    float* __restrict__ q, float* __restrict__ k,
    const float* __restrict__ q_gain) {
  int bt = blockIdx.x;
  int t = bt % Tc;
  int tid = threadIdx.x;
  int lane = tid & 63, wv = tid >> 6;
  int fi = lane & 31;
  float inv = expf(-(float)(2 * fi) * (9.210340372f / 64.f));
  float ang = (float)t * inv;
  float cv = cosf(ang);
  float sv = sinf(ang);

#pragma unroll
  for (int hh = 0; hh < 4; ++hh) {
    int h = wv + hh * 4;
    float* qp = q + (size_t)bt * Dc + h * 64;
    float val = qp[lane];
    float ss = wave_sum(val * val);
    float rn = rsqrtf(ss / 64.f + 1e-6f);
    val *= rn;
    float partner = __shfl(val, lane ^ 32);
    float out = (lane < 32) ? (val * cv + partner * sv) : (val * cv - partner * sv);
    out *= q_gain[h];
    qp[lane] = out;
  }
  {
    int h = wv;
    float* kp = k + (size_t)bt * KVDc + h * 64;
    float val = kp[lane];
    float ss = wave_sum(val * val);
    float rn = rsqrtf(ss / 64.f + 1e-6f);
    val *= rn;
    float partner = __shfl(val, lane ^ 32);
    float out = (lane < 32) ? (val * cv + partner * sv) : (val * cv - partner * sv);
    kp[lane] = out;
  }
}

// ---------------------------------------------------------------------------
// K/V^T frag-order plane prep (unchanged).
// ---------------------------------------------------------------------------
__global__ __launch_bounds__(256) void kvprep_kernel(
    const float* __restrict__ kb, const float* __restrict__ vb,
    short* __restrict__ khG, short* __restrict__ klG,
    short* __restrict__ vthG, short* __restrict__ vtlG) {
  __shared__ float kf[64][65];
  __shared__ float vf[64][65];
  int kt = blockIdx.x, bh = blockIdx.y;
  int b = bh >> 2, hkv = bh & 3;
  int tid = threadIdx.x;
#pragma unroll
  for (int u = 0; u < 4; ++u) {
    int idx = tid + u * 256;
    int row = idx >> 4, c4 = idx & 15;
    size_t off = ((size_t)(b * Tc + kt * 64 + row)) * KVDc + hkv * 64 + c4 * 4;
    float4 k4 = *(const float4*)(kb + off);
    float4 v4 = *(const float4*)(vb + off);
    kf[row][c4 * 4 + 0] = k4.x; kf[row][c4 * 4 + 1] = k4.y;
    kf[row][c4 * 4 + 2] = k4.z; kf[row][c4 * 4 + 3] = k4.w;
    vf[row][c4 * 4 + 0] = v4.x; vf[row][c4 * 4 + 1] = v4.y;
    vf[row][c4 * 4 + 2] = v4.z; vf[row][c4 * 4 + 3] = v4.w;
  }
  __syncthreads();
  size_t gb = ((size_t)(bh * (Tc / 64) + kt)) * 4096;
#pragma unroll
  for (int u = 0; u < 2; ++u) {
    int unit = tid + u * 256;
    int s = unit >> 6, p = unit & 63;
    {
      int half = s >> 2, rg = s & 3;
      int row = rg * 16 + (p & 15);
      int d0 = half * 32 + (p >> 4) * 8;
      short8 h8, l8;
#pragma unroll
      for (int e = 0; e < 8; ++e) {
        float v = kf[row][d0 + e];
        short hb = f2bf(v);
        h8[e] = hb;
        l8[e] = f2bf(v - bf2f(hb));
      }
      *(short8*)(khG + gb + s * 512 + p * 8) = h8;
      *(short8*)(klG + gb + s * 512 + p * 8) = l8;
    }
    {
      int ks = s >> 2, jd = s & 3;
      int d = jd * 16 + (p & 15);
      int k0 = ks * 32 + (p >> 4) * 8;
      short8 h8, l8;
#pragma unroll
      for (int e = 0; e < 8; ++e) {
        float v = vf[k0 + e][d];
        short hb = f2bf(v);
        h8[e] = hb;
        l8[e] = f2bf(v - bf2f(hb));
      }
      *(short8*)(vthG + gb + s * 512 + p * 8) = h8;
      *(short8*)(vtlG + gb + s * 512 + p * 8) = l8;
    }
  }
}

// ---------------------------------------------------------------------------
// MFMA causal GQA flash attention + v-direction-removal epilogue.
// y output written directly in FRAG-ORDER planes (consumed by wp_frag).
// ---------------------------------------------------------------------------
__global__ __launch_bounds__(256) void attn_mfma(
    const float* __restrict__ qg_, const float* __restrict__ vg_,
    const short* __restrict__ khG, const short* __restrict__ klG,
    const short* __restrict__ vthG, const short* __restrict__ vtlG,
    short* __restrict__ yh_, short* __restrict__ yl_) {
  __shared__ short smem[24576];  // 48 KiB
  short* Khi  = smem;
  short* Klo  = smem + 4096;
  short* Vthi = smem + 8192;
  short* Vtlo = smem + 12288;

  int bh = blockIdx.x;
  int qt = (gridDim.y - 1) - blockIdx.y;
  int b = bh >> 2, hkv = bh & 3;
  int tid = threadIdx.x;
  int lane = tid & 63, wv = tid >> 6;
  int x = lane & 15, g = lane >> 4;
  int h = hkv * 4 + wv;
  int qbase = qt * 16;

  short* PAhi = smem + 16384 + wv * 1024;
  short* PAlo = smem + 20480 + wv * 1024;

  short8 qh[2], qlo[2];
#pragma unroll
  for (int ks = 0; ks < 2; ++ks) {
    int qrow = qbase + x;
    const float* qp =
        qg_ + ((size_t)(b * Tc + qrow)) * Dc + h * 64 + ks * 32 + g * 8;
    float4 f0 = *(const float4*)qp;
    float4 f1 = *(const float4*)(qp + 4);
    float fv[8] = {f0.x, f0.y, f0.z, f0.w, f1.x, f1.y, f1.z, f1.w};
#pragma unroll
    for (int e = 0; e < 8; ++e) {
      short hb = f2bf(fv[e]);
      qh[ks][e] = hb;
      qlo[ks][e] = f2bf(fv[e] - bf2f(hb));
    }
  }

  const short* planes[4] = {khG, klG, vthG, vtlG};
  const short* gplane = planes[wv] + ((size_t)bh * (Tc / 64)) * 4096 + lane * 8;
  short* lplane = smem + wv * 4096;

  floatx4 o[4] = {};
  float m_run = NEG_BIG, l_run = 0.f;

  int nkt = (qbase >> 6) + 1;
  for (int kt = 0; kt < nkt; ++kt) {
    const short* gs = gplane + (size_t)kt * 4096;
#pragma unroll
    for (int t = 0; t < 8; ++t) gll16(gs + t * 512, lplane + t * 512);
    __syncthreads();

    floatx4 st[4] = {};
#pragma unroll
    for (int ks = 0; ks < 2; ++ks) {
#pragma unroll
      for (int i = 0; i < 4; ++i) {
        short8 ka_h = *(const short8*)(Khi + ks * 2048 + i * 512 + lane * 8);
        short8 ka_l = *(const short8*)(Klo + ks * 2048 + i * 512 + lane * 8);
        st[i] = __builtin_amdgcn_mfma_f32_16x16x32_bf16(ka_h, qh[ks], st[i], 0, 0, 0);
        st[i] = __builtin_amdgcn_mfma_f32_16x16x32_bf16(ka_h, qlo[ks], st[i], 0, 0, 0);
        st[i] = __builtin_amdgcn_mfma_f32_16x16x32_bf16(ka_l, qh[ks], st[i], 0, 0, 0);
      }
    }

    float alv;
    {
      int qrow = qbase + x;
      float mx = NEG_BIG;
#pragma unroll
      for (int i = 0; i < 4; ++i) {
#pragma unroll
        for (int r = 0; r < 4; ++r) {
          int krow = kt * 64 + 16 * i + 4 * g + r;
          float s = st[i][r] * 0.125f;
          if (krow > qrow) s = NEG_BIG;
          st[i][r] = s;
          mx = fmaxf(mx, s);
        }
      }
      mx = fmaxf(mx, __shfl_xor(mx, 16));
      mx = fmaxf(mx, __shfl_xor(mx, 32));
      float m_new = fmaxf(m_run, mx);
      alv = __expf(m_run - m_new);
      float ts = 0.f;
#pragma unroll
      for (int i = 0; i < 4; ++i) {
#pragma unroll
        for (int r = 0; r < 4; ++r) {
          float p = __expf(st[i][r] - m_new);
          st[i][r] = p;
          ts += p;
        }
      }
      ts += __shfl_xor(ts, 16);
      ts += __shfl_xor(ts, 32);
      l_run = l_run * alv + ts;
      m_run = m_new;
    }

#pragma unroll
    for (int i = 0; i < 4; ++i) {
      short4v h4, l4;
#pragma unroll
      for (int r = 0; r < 4; ++r) {
        float p = st[i][r];
        short hb = f2bf(p);
        h4[r] = hb;
        l4[r] = f2bf(p - bf2f(hb));
      }
      int offp = (i >> 1) * 512 +
                 (x + (2 * (i & 1) + (g >> 1)) * 16) * 8 + 4 * (g & 1);
      *(short4v*)(PAhi + offp) = h4;
      *(short4v*)(PAlo + offp) = l4;
    }

#pragma unroll
    for (int r = 0; r < 4; ++r) {
      float a = __shfl(alv, 4 * g + r);
#pragma unroll
      for (int jd = 0; jd < 4; ++jd) o[jd][r] *= a;
    }
    __syncthreads();

#pragma unroll
    for (int ks = 0; ks < 2; ++ks) {
      short8 pa_h = *(const short8*)(PAhi + ks * 512 + lane * 8);
      short8 pa_l = *(const short8*)(PAlo + ks * 512 + lane * 8);
#pragma unroll
      for (int jd = 0; jd < 4; ++jd) {
        short8 vb_h = *(const short8*)(Vthi + ks * 2048 + jd * 512 + lane * 8);
        short8 vb_l = *(const short8*)(Vtlo + ks * 2048 + jd * 512 + lane * 8);
        o[jd] = __builtin_amdgcn_mfma_f32_16x16x32_bf16(pa_h, vb_h, o[jd], 0, 0, 0);
        o[jd] = __builtin_amdgcn_mfma_f32_16x16x32_bf16(pa_h, vb_l, o[jd], 0, 0, 0);
        o[jd] = __builtin_amdgcn_mfma_f32_16x16x32_bf16(pa_l, vb_h, o[jd], 0, 0, 0);
      }
    }
    __syncthreads();
  }

  // finalize: /l_run, remove v-component, store y in FRAG-ORDER planes.
#pragma unroll
  for (int r = 0; r < 4; ++r) {
    float lr = __shfl(l_run, 4 * g + r);
    float rcp = 1.f / lr;
    int qrow = qbase + 4 * g + r;
    const float* vr = vg_ + ((size_t)(b * Tc + qrow)) * KVDc + hkv * 64;
    float vv[4], oo[4];
    float pn = 0.f, pd = 0.f;
#pragma unroll
    for (int jd = 0; jd < 4; ++jd) {
      vv[jd] = vr[16 * jd + x];
      oo[jd] = o[jd][r] * rcp;
      pn += vv[jd] * vv[jd];
      pd += oo[jd] * vv[jd];
    }
#pragma unroll
    for (int off = 1; off <= 8; off <<= 1) {
      pn += __shfl_xor(pn, off);
      pd += __shfl_xor(pd, off);
    }
    float nrm = sqrtf(pn);
    float mxv = fmaxf(nrm, 1e-12f);
    float si = 1.f / mxv;
    float co = pd * si * si;
    int grow = b * Tc + qrow;
    size_t fb = ((size_t)(grow >> 5)) * 64 * 512 +
                ((size_t)(grow & 31) + 32 * (x >> 3)) * 8 + (x & 7);
#pragma unroll
    for (int jd = 0; jd < 4; ++jd) {
      float val = oo[jd] - co * vv[jd];
      short hb = f2bf(val);
      size_t off = fb + (size_t)(h * 4 + jd) * 512;
      yh_[off] = hb;
      yl_[off] = f2bf(val - bf2f(hb));
    }
  }
}

// ---------------------------------------------------------------------------
extern "C" void kernel_launch(void* const* d_in, const int* in_sizes, int n_in,
                              void* d_out, int out_size, void* d_ws,
                              size_t ws_size, hipStream_t stream) {
  const int* ids          = (const int*)d_in[0];
  const float* embed_w    = (const float*)d_in[1];
  const float* big_w      = (const float*)d_in[2];
  const float* big_proj   = (const float*)d_in[3];
  const float* big_scale  = (const float*)d_in[4];
  const float* smear_gate = (const float*)d_in[5];
  const float* ve_w       = (const float*)d_in[6];
  const float* ve_proj    = (const float*)d_in[7];
  const float* ve_scale   = (const float*)d_in[8];
  const float* Wq         = (const float*)d_in[9];
  const float* Wk         = (const float*)d_in[10];
  const float* Wv         = (const float*)d_in[11];
  const float* Wo         = (const float*)d_in[12];
  const float* q_gain     = (const float*)d_in[13];
  const float* attn_scale = (const float*)d_in[14];
  const float* mlp_scale  = (const float*)d_in[15];
  const float* resid_mix  = (const float*)d_in[16];
  const float* Wfc        = (const float*)d_in[17];
  const float* Wp         = (const float*)d_in[18];
  const float* head_w     = (const float*)d_in[19];
  float* out = (float*)d_out;

  // ---- workspace layout ----
  char* p = (char*)d_ws;
  float* x     = (float*)p; p += SZ_X * 4;
  float* x0    = (float*)p; p += SZ_X * 4;
  float* x_in  = (float*)p; p += SZ_X * 4;
  float* qb    = (float*)p; p += SZ_X * 4;
  float* kb    = (float*)p; p += SZ_KV * 4;
  float* vb    = (float*)p; p += SZ_KV * 4;
  float* vemb  = (float*)p; p += SZ_KV * 4;
  float* raw_x = (float*)p; p += SZ_X * 4;
  short* xnh = (short*)p; p += SZ_X * 2;   // frag-order
  short* xnl = (short*)p; p += SZ_X * 2;
  short* yh  = (short*)p; p += SZ_X * 2;   // frag-order
  short* yl  = (short*)p; p += SZ_X * 2;
  short* hh  = (short*)p; p += SZ_H * 2;   // frag-order
  short* hl  = (short*)p; p += SZ_H * 2;
  short* khG  = (short*)p; p += SZ_KVP * 2;
  short* klG  = (short*)p; p += SZ_KVP * 2;
  short* vthG = (short*)p; p += SZ_KVP * 2;
  short* vtlG = (short*)p; p += SZ_KVP * 2;
  short* wqh = (short*)p; p += W_Q * 2;
  short* wql = (short*)p; p += W_Q * 2;
  short* wkh = (short*)p; p += W_KV * 2;
  short* wkl = (short*)p; p += W_KV * 2;
  short* wvh = (short*)p; p += W_KV * 2;
  short* wvl = (short*)p; p += W_KV * 2;
  short* woh = (short*)p; p += W_Q * 2;
  short* wol = (short*)p; p += W_Q * 2;
  short* wfh = (short*)p; p += W_FC * 2;
  short* wfl = (short*)p; p += W_FC * 2;
  short* wph = (short*)p; p += W_FC * 2;
  short* wpl = (short*)p; p += W_FC * 2;
  short* hwh = (short*)p; p += W_HD * 2;
  short* hwl = (short*)p; p += W_HD * 2;

  // ---- weight conversion: BATCHED over all layers (7 launches total).
  auto wcf = [&](const float* s, short* h, short* l2, int N, int Npad, int K) {
    long n8 = (long)Npad * (K >> 3);
    int blocks = (int)((n8 + 255) / 256);
    wcvt_frag_kernel<<<blocks, 256, 0, stream>>>(s, h, l2, N, Npad, K);
  };
  wcf(Wq, wqh, wql, Lc * Dc, Lc * Dc, Dc);
  wcf(Wk, wkh, wkl, Lc * KVDc, Lc * KVDc, Dc);
  wcf(Wv, wvh, wvl, Lc * KVDc, Lc * KVDc, Dc);
  wcf(Wo, woh, wol, Lc * Dc, Lc * Dc, Dc);
  wcf(Wfc, wfh, wfl, Lc * MLPc, Lc * MLPc, Dc);
  wcf(Wp, wph, wpl, Lc * Dc, Lc * Dc, MLPc);
  wcf(head_w, hwh, hwl, Vc, VPAD, Dc);

  embed_kernel<<<NTOK, 256, 0, stream>>>(ids, embed_w, big_w, big_proj,
                                         big_scale, ve_w, ve_proj, ve_scale,
                                         raw_x, vemb);
  smear_kernel<<<(int)(SZ_X / 256), 256, 0, stream>>>(raw_x, smear_gate, x, x0);

  for (int l = 0; l < Lc; ++l) {
    const float* mix = resid_mix + (size_t)l * 2 * Dc;
    prelayer_kernel<<<NTOK, 256, 0, stream>>>(x, x0, mix, x_in, xnh, xnl);
    qkv_frag<<<dim3(NTOK / 64, 12), 256, 0, stream>>>(
        xnh, xnl, wqh + (size_t)l * Dc * Dc, wql + (size_t)l * Dc * Dc,
        wkh + (size_t)l * KVDc * Dc, wkl + (size_t)l * KVDc * Dc,
        wvh + (size_t)l * KVDc * Dc, wvl + (size_t)l * KVDc * Dc, qb, kb, vb,
        vemb, Dc);
    qkrope_kernel<<<NTOK, 256, 0, stream>>>(qb, kb, q_gain + (size_t)l * Hc);
    kvprep_kernel<<<dim3(Tc / 64, Bc * HKVc), 256, 0, stream>>>(
        kb, vb, khG, klG, vthG, vtlG);
    attn_mfma<<<dim3(Bc * HKVc, Tc / 16), 256, 0, stream>>>(
        qb, vb, khG, klG, vthG, vtlG, yh, yl);
    // out proj + residual: x = x_in + attn_scale * (y @ Wo.T)
    wp_frag<<<dim3(NTOK / 64, Dc / 128), 256, 0, stream>>>(
        yh, yl, woh + (size_t)l * Dc * Dc, wol + (size_t)l * Dc * Dc, x, x_in,
        attn_scale + (size_t)l * Dc, Dc, Dc);
    // MLP
    rms_split_kernel<<<NTOK, 256, 0, stream>>>(x, xnh, xnl);
    fc_frag<<<dim3(NTOK / 128, MLPc / 256), 256, 0, stream>>>(
        xnh, xnl, wfh + (size_t)l * MLPc * Dc, wfl + (size_t)l * MLPc * Dc, hh,
        hl, MLPc, Dc, MLPc >> 4);
    wp_frag<<<dim3(NTOK / 64, Dc / 128), 256, 0, stream>>>(
        hh, hl, wph + (size_t)l * Dc * MLPc, wpl + (size_t)l * Dc * MLPc, x, x,
        mlp_scale + (size_t)l * Dc, Dc, MLPc);
  }

  rms_split_kernel<<<NTOK, 256, 0, stream>>>(x, xnh, xnl);
  head_frag<<<dim3(NTOK / 128, VPAD / 256), 256, 0, stream>>>(
      xnh, xnl, hwh, hwl, out, Vc, Dc);
}

// Round 13
// 4281.154 us; speedup vs baseline: 1.0107x; 1.0107x over previous
//
#include <hip/hip_runtime.h>
#include <hip/hip_bf16.h>

// Problem constants (match reference)
constexpr int Bc   = 2;
constexpr int Tc   = 1024;
constexpr int Vc   = 50257;
constexpr int Lc   = 8;
constexpr int Dc   = 1024;
constexpr int Hc   = 16;
constexpr int HKVc = 4;
constexpr int HDc  = 64;     // D/H
constexpr int KVDc = 256;    // HKV*HD
constexpr int MLPc = 4096;   // 4*D
constexpr int BVc  = 65536;
constexpr int BDc  = 256;
constexpr int VEDc = 128;

constexpr int NTOK = Bc * Tc;          // 2048
constexpr long SZ_X  = (long)NTOK * Dc;    // 2,097,152
constexpr long SZ_KV = (long)NTOK * KVDc;  // 524,288
constexpr long SZ_H  = (long)NTOK * MLPc;  // 8,388,608

constexpr int  VPAD = 50432;                  // Vc padded to 256
constexpr long W_Q  = (long)Lc * Dc * Dc;     // 8,388,608
constexpr long W_KV = (long)Lc * KVDc * Dc;   // 2,097,152
constexpr long W_FC = (long)Lc * MLPc * Dc;   // 33,554,432
constexpr long W_HD = (long)VPAD * Dc;        // frag-order, padded
constexpr long SZ_KVP = (long)Bc * HKVc * (Tc / 64) * 4096;  // shorts/plane

#define NEG_BIG (-3.0e38f)

typedef __attribute__((ext_vector_type(8))) short short8;    // 8 bf16 (4 VGPRs)
typedef __attribute__((ext_vector_type(4))) short short4v;   // 4 bf16 (8 B)
typedef __attribute__((ext_vector_type(4))) float floatx4;   // 16x16 MFMA acc
typedef __attribute__((ext_vector_type(16))) float floatx16; // 32x32 MFMA acc

__device__ __forceinline__ float wave_sum(float v) {
#pragma unroll
  for (int off = 32; off >= 1; off >>= 1) v += __shfl_xor(v, off);
  return v;
}

// Bijective XCD-aware swizzle (m204 formula).
__device__ __forceinline__ void xcd_swizzle(int& bx, int& by, int nbx, int nby) {
  int n = nbx * nby;
  int lin = by * nbx + bx;
  int q = n >> 3, rm = n & 7;
  int xcd = lin & 7, idx = lin >> 3;
  int v = (xcd < rm) ? (xcd * (q + 1) + idx)
                     : (rm * (q + 1) + (xcd - rm) * q + idx);
  bx = v % nbx;
  by = v / nbx;
}

// async global->LDS, 16B per lane. LDS dest = wave-uniform base + lane*16.
__device__ __forceinline__ void gll16(const void* g, void* l) {
  __builtin_amdgcn_global_load_lds(
      (const __attribute__((address_space(1))) unsigned int*)g,
      (__attribute__((address_space(3))) unsigned int*)l, 16, 0, 0);
}

// ---------------------------------------------------------------------------
// bf16 split helpers: f = bf2f(hi) + bf2f(lo) + O(2^-17 * f)
// ---------------------------------------------------------------------------
__device__ __forceinline__ short f2bf(float f) {
  unsigned u = __float_as_uint(f);
  return (short)((u + 0x7fffu + ((u >> 16) & 1u)) >> 16);
}
__device__ __forceinline__ float bf2f(short h) {
  return __uint_as_float(((unsigned)(unsigned short)h) << 16);
}

// ---------------------------------------------------------------------------
// Weight conversion: fp32 row-major [N][K] -> frag-order hi/lo planes
//   layout [Npad/32][K/16][64 lanes][8 shorts]; lane = (r&31) + 32*(k8&1).
// Layer-contiguous: batched over all layers in ONE launch.
// ---------------------------------------------------------------------------
__global__ __launch_bounds__(256) void wcvt_frag_kernel(
    const float* __restrict__ src, short* __restrict__ hi,
    short* __restrict__ lo, int N, int Npad, int K) {
  long i = (long)blockIdx.x * 256 + threadIdx.x;
  int K8 = K >> 3;
  long n8 = (long)Npad * K8;
  if (i >= n8) return;
  int r = (int)(i / K8);
  int k8 = (int)(i % K8);
  float fv[8] = {};
  if (r < N) {
    const float* s = src + (size_t)r * K + k8 * 8;
    float4 f0 = *(const float4*)s;
    float4 f1 = *(const float4*)(s + 4);
    fv[0] = f0.x; fv[1] = f0.y; fv[2] = f0.z; fv[3] = f0.w;
    fv[4] = f1.x; fv[5] = f1.y; fv[6] = f1.z; fv[7] = f1.w;
  }
  short8 h8, l8;
#pragma unroll
  for (int e = 0; e < 8; ++e) {
    short hb = f2bf(fv[e]);
    h8[e] = hb;
    l8[e] = f2bf(fv[e] - bf2f(hb));
  }
  int rg = r >> 5, ksi = k8 >> 1;
  int lanev = (r & 31) + ((k8 & 1) << 5);
  size_t off = (((size_t)rg * (K >> 4) + ksi) * 64 + lanev) * 8;
  *(short8*)(hi + off) = h8;
  *(short8*)(lo + off) = l8;
}

// ---------------------------------------------------------------------------
// Embedding (unchanged)
// ---------------------------------------------------------------------------
__global__ __launch_bounds__(256) void embed_kernel(
    const int* __restrict__ ids, const float* __restrict__ embed_w,
    const float* __restrict__ big_w, const float* __restrict__ big_proj,
    const float* __restrict__ big_scale, const float* __restrict__ ve_w,
    const float* __restrict__ ve_proj, const float* __restrict__ ve_scale,
    float* __restrict__ raw_x, float* __restrict__ vemb) {
  int bt = blockIdx.x;
  int tid = threadIdx.x;
  int t = bt % Tc;
  int tok = ids[bt];

  const float* e = embed_w + (size_t)tok * Dc;
  float ev[4];
  float ss = 0.f;
#pragma unroll
  for (int i = 0; i < 4; ++i) {
    ev[i] = e[tid + i * 256];
    ss += ev[i] * ev[i];
  }
  __shared__ float red[4];
  __shared__ float brow[BDc];
  __shared__ float verow[VEDc];
  float wsum = wave_sum(ss);
  if ((tid & 63) == 0) red[tid >> 6] = wsum;

  int bg;
  if (t == 0) {
    bg = BVc - 1;
  } else {
    unsigned a = (unsigned)ids[bt];
    unsigned p = (unsigned)ids[bt - 1];
    bg = (int)(((36313u * a) ^ (27191u * p)) % 65535u);
  }
  brow[tid] = big_w[(size_t)bg * BDc + tid];
  if (tid < VEDc) verow[tid] = ve_w[(size_t)tok * VEDc + tid];
  __syncthreads();

  float tot = red[0] + red[1] + red[2] + red[3];
  float rn = rsqrtf(tot / (float)Dc + 1e-6f);
  float bs = big_scale[0];
#pragma unroll
  for (int i = 0; i < 4; ++i) {
    int d = tid + i * 256;
    const float* bp = big_proj + (size_t)d * BDc;
    float dot = 0.f;
    for (int c = 0; c < BDc; ++c) dot += brow[c] * bp[c];
    raw_x[(size_t)bt * Dc + d] = ev[i] * rn + dot * bs;
  }
  {
    float vs = ve_scale[0];
    int d = tid;
    const float* vp = ve_proj + (size_t)d * VEDc;
    float dot = 0.f;
    for (int c = 0; c < VEDc; ++c) dot += verow[c] * vp[c];
    vemb[(size_t)bt * KVDc + d] = dot * vs;
  }
}

// ---------------------------------------------------------------------------
// Smear (unchanged)
// ---------------------------------------------------------------------------
__global__ __launch_bounds__(256) void smear_kernel(
    const float* __restrict__ raw, const float* __restrict__ gate,
    float* __restrict__ x, float* __restrict__ x0) {
  long idx = (long)blockIdx.x * 256 + threadIdx.x;
  if (idx >= SZ_X) return;
  int d = (int)(idx & (Dc - 1));
  int t = (int)((idx / Dc) & (Tc - 1));
  float g = 1.f / (1.f + expf(-gate[d]));
  float cur = raw[idx];
  float prev = (t > 0) ? raw[idx - Dc] : 0.f;
  float val = (1.f - g) * cur + g * prev;
  x[idx] = val;
  x0[idx] = val;
}

// ---------------------------------------------------------------------------
// frag-order activation store: token bt, 4 consecutive elems at d0=4*tid.
// ---------------------------------------------------------------------------
__device__ __forceinline__ void store_frag4(short* __restrict__ ph,
                                            short* __restrict__ pl, int bt,
                                            int d0, int K16, const float* v) {
  short4v h4, l4;
#pragma unroll
  for (int e = 0; e < 4; ++e) {
    short hb = f2bf(v[e]);
    h4[e] = hb;
    l4[e] = f2bf(v[e] - bf2f(hb));
  }
  int lanev = (bt & 31) + 32 * ((d0 >> 3) & 1);
  size_t off = (((size_t)(bt >> 5) * K16 + (d0 >> 4)) * 64 + lanev) * 8 + (d0 & 7);
  *(short4v*)(ph + off) = h4;
  *(short4v*)(pl + off) = l4;
}

// ---------------------------------------------------------------------------
// Pre-layer: x_in = mix0*x + mix1*x0 ; xn frag planes = split(rms(x_in)).
// ---------------------------------------------------------------------------
__global__ __launch_bounds__(256) void prelayer_kernel(
    const float* __restrict__ x, const float* __restrict__ x0,
    const float* __restrict__ mix, float* __restrict__ x_in,
    short* __restrict__ xnh, short* __restrict__ xnl) {
  int bt = blockIdx.x;
  int tid = threadIdx.x;
  int d0 = tid * 4;
  const float* xr = x + (size_t)bt * Dc;
  const float* x0r = x0 + (size_t)bt * Dc;
  float4 xv = *(const float4*)(xr + d0);
  float4 x0v = *(const float4*)(x0r + d0);
  float4 m0 = *(const float4*)(mix + d0);
  float4 m1 = *(const float4*)(mix + Dc + d0);
  float vals[4] = {m0.x * xv.x + m1.x * x0v.x, m0.y * xv.y + m1.y * x0v.y,
                   m0.z * xv.z + m1.z * x0v.z, m0.w * xv.w + m1.w * x0v.w};
  float ss = vals[0] * vals[0] + vals[1] * vals[1] + vals[2] * vals[2] +
             vals[3] * vals[3];
  __shared__ float red[4];
  float wsum = wave_sum(ss);
  if ((tid & 63) == 0) red[tid >> 6] = wsum;
  __syncthreads();
  float tot = red[0] + red[1] + red[2] + red[3];
  float rn = rsqrtf(tot / (float)Dc + 1e-6f);
  *(float4*)(x_in + (size_t)bt * Dc + d0) =
      make_float4(vals[0], vals[1], vals[2], vals[3]);
  float vn[4] = {vals[0] * rn, vals[1] * rn, vals[2] * rn, vals[3] * rn};
  store_frag4(xnh, xnl, bt, d0, Dc >> 4, vn);
}

// ---------------------------------------------------------------------------
// RMS over D -> frag-order bf16 hi/lo planes. Block per token.
// ---------------------------------------------------------------------------
__global__ __launch_bounds__(256) void rms_split_kernel(
    const float* __restrict__ in, short* __restrict__ oh,
    short* __restrict__ ol) {
  int bt = blockIdx.x;
  int tid = threadIdx.x;
  int d0 = tid * 4;
  float4 v4 = *(const float4*)(in + (size_t)bt * Dc + d0);
  float v[4] = {v4.x, v4.y, v4.z, v4.w};
  float ss = v[0] * v[0] + v[1] * v[1] + v[2] * v[2] + v[3] * v[3];
  __shared__ float red[4];
  float wsum = wave_sum(ss);
  if ((tid & 63) == 0) red[tid >> 6] = wsum;
  __syncthreads();
  float tot = red[0] + red[1] + red[2] + red[3];
  float rn = rsqrtf(tot / (float)Dc + 1e-6f);
  float vn[4] = {v[0] * rn, v[1] * rn, v[2] * rn, v[3] * rn};
  store_frag4(oh, ol, bt, d0, Dc >> 4, vn);
}

// ---------------------------------------------------------------------------
// Frag-order GEMM core (R9/R11 structure; best verified at 49% MfmaUtil).
// A and B BOTH in frag-order global planes [R/32][K/16][64][8]; every
// global_load_lds is ONE contiguous 1KB packet. Counted-vmcnt double-buffered
// pipeline: tile k waited with vmcnt(SPW) while k+1 stays in flight; k+2
// staged into the freed buffer after the read-barrier. 2 blocks/CU give the
// 2-waves/SIMD overlap the port-cap requires (R12 lesson: 1 wave/SIMD
// serializes ds_read and MFMA and loses ~20%).
// ---------------------------------------------------------------------------
template <int BM, int BN>
__device__ __forceinline__ void gemm_frag_core(
    const short* __restrict__ Afh, const short* __restrict__ Afl,
    const short* __restrict__ Bfh, const short* __restrict__ Bfl, int m0,
    int n0, int K, short* lds, floatx16 (*acc)[BN / 64]) {
  constexpr int RGA = BM / 32;
  constexpr int RGB = BN / 32;
  constexpr int SPW = RGA + RGB;        // gll16 per wave per tile
  constexpr int PLA = RGA * 1024;
  constexpr int PLB = RGB * 1024;
  constexpr int HB = 2 * (PLA + PLB);   // shorts per buffer
  constexpr int FI = BM / 64;
  constexpr int FJ = BN / 64;

  int tid = threadIdx.x, lane = tid & 63, wv = tid >> 6;
  int K16 = K >> 4;

  const short* gsrc[SPW];
  int ldst[SPW];
#pragma unroll
  for (int t = 0; t < SPW; ++t) {
    int s = wv * SPW + t;
    const short* plane;
    int poff, rg, ks;
    size_t base;
    if (s < RGA * 4) {
      int p = s / (RGA * 2);
      int rem = s % (RGA * 2);
      rg = rem >> 1; ks = rem & 1;
      plane = p ? Afl : Afh;
      poff = p ? PLA : 0;
      base = (((size_t)(m0 >> 5) + rg) * K16 + ks) * 512;
    } else {
      int s2 = s - RGA * 4;
      int p = s2 / (RGB * 2);
      int rem = s2 % (RGB * 2);
      rg = rem >> 1; ks = rem & 1;
      plane = p ? Bfl : Bfh;
      poff = 2 * PLA + (p ? PLB : 0);
      base = (((size_t)(n0 >> 5) + rg) * K16 + ks) * 512;
    }
    gsrc[t] = plane + base + lane * 8;
    ldst[t] = poff + (rg * 2 + ks) * 512;
  }

  int wm = (wv >> 1) * (BM / 2), wn = (wv & 1) * (BN / 2);

  // prologue: tile 0 -> buf0, tile 1 -> buf1 (K >= 64 everywhere here)
#pragma unroll
  for (int t = 0; t < SPW; ++t) gll16(gsrc[t], lds + ldst[t]);
#pragma unroll
  for (int t = 0; t < SPW; ++t) gsrc[t] += 1024;
#pragma unroll
  for (int t = 0; t < SPW; ++t) gll16(gsrc[t], lds + HB + ldst[t]);
#pragma unroll
  for (int t = 0; t < SPW; ++t) gsrc[t] += 1024;

  int cur = 0;
  for (int k0 = 0; k0 < K; k0 += 32) {
    if (k0 + 32 < K) {
      if constexpr (SPW == 8) {
        asm volatile("s_waitcnt vmcnt(8)" ::: "memory");
      } else {
        asm volatile("s_waitcnt vmcnt(6)" ::: "memory");
      }
    } else {
      asm volatile("s_waitcnt vmcnt(0)" ::: "memory");
    }
    __builtin_amdgcn_s_barrier();
    __builtin_amdgcn_sched_barrier(0);

    const short* As_h = lds + cur * HB;
    const short* As_l = As_h + PLA;
    const short* Bs_h = As_h + 2 * PLA;
    const short* Bs_l = Bs_h + PLB;
    short8 ah[2][FI], alx[2][FI], bhx[2][FJ], blx[2][FJ];
#pragma unroll
    for (int ks = 0; ks < 2; ++ks) {
#pragma unroll
      for (int i = 0; i < FI; ++i) {
        int rg = (wm >> 5) + i;
        ah[ks][i]  = *(const short8*)(As_h + (rg * 2 + ks) * 512 + lane * 8);
        alx[ks][i] = *(const short8*)(As_l + (rg * 2 + ks) * 512 + lane * 8);
      }
#pragma unroll
      for (int j = 0; j < FJ; ++j) {
        int rg = (wn >> 5) + j;
        bhx[ks][j] = *(const short8*)(Bs_h + (rg * 2 + ks) * 512 + lane * 8);
        blx[ks][j] = *(const short8*)(Bs_l + (rg * 2 + ks) * 512 + lane * 8);
      }
    }
    asm volatile("s_waitcnt lgkmcnt(0)" ::: "memory");
    __builtin_amdgcn_sched_barrier(0);
    __builtin_amdgcn_s_barrier();  // all waves done reading buf[cur]

    if (k0 + 64 < K) {  // stage tile k+2 into freed buffer
#pragma unroll
      for (int t = 0; t < SPW; ++t) gll16(gsrc[t], lds + cur * HB + ldst[t]);
#pragma unroll
      for (int t = 0; t < SPW; ++t) gsrc[t] += 1024;
    }
    __builtin_amdgcn_sched_barrier(0);

    __builtin_amdgcn_s_setprio(1);
#pragma unroll
    for (int ks = 0; ks < 2; ++ks) {
#pragma unroll
      for (int i = 0; i < FI; ++i)
#pragma unroll
        for (int j = 0; j < FJ; ++j)
          acc[i][j] = __builtin_amdgcn_mfma_f32_32x32x16_bf16(ah[ks][i], bhx[ks][j], acc[i][j], 0, 0, 0);
#pragma unroll
      for (int i = 0; i < FI; ++i)
#pragma unroll
        for (int j = 0; j < FJ; ++j)
          acc[i][j] = __builtin_amdgcn_mfma_f32_32x32x16_bf16(ah[ks][i], blx[ks][j], acc[i][j], 0, 0, 0);
#pragma unroll
      for (int i = 0; i < FI; ++i)
#pragma unroll
        for (int j = 0; j < FJ; ++j)
          acc[i][j] = __builtin_amdgcn_mfma_f32_32x32x16_bf16(alx[ks][i], bhx[ks][j], acc[i][j], 0, 0, 0);
    }
    __builtin_amdgcn_s_setprio(0);
    cur ^= 1;
  }
}

// head GEMM: 128x128, fp32 C with column guard.
__global__ __launch_bounds__(256, 2) void head_frag(
    const short* __restrict__ Afh, const short* __restrict__ Afl,
    const short* __restrict__ Bfh, const short* __restrict__ Bfl,
    float* __restrict__ C, int N, int K) {
  __shared__ short lds[32768];  // 64 KiB
  int bx = blockIdx.x, by = blockIdx.y;
  xcd_swizzle(bx, by, gridDim.x, gridDim.y);
  int m0 = bx * 128, n0 = by * 128;
  floatx16 acc[2][2] = {};
  gemm_frag_core<128, 128>(Afh, Afl, Bfh, Bfl, m0, n0, K, lds, acc);
  int lane = threadIdx.x & 63, wv = threadIdx.x >> 6;
  int wm = (wv >> 1) * 64, wn = (wv & 1) * 64;
  int cl = lane & 31, g2 = lane >> 5;
#pragma unroll
  for (int i = 0; i < 2; ++i)
#pragma unroll
    for (int j = 0; j < 2; ++j) {
      int col = n0 + wn + 32 * j + cl;
      if (col >= N) continue;
      floatx16 f = acc[i][j];
#pragma unroll
      for (int r = 0; r < 16; ++r) {
        int row = m0 + wm + 32 * i + (r & 3) + 8 * (r >> 2) + 4 * g2;
        C[(size_t)row * N + col] = f[r];
      }
    }
}

// Wp GEMM: 64x128, fp32 C = base + colscale * acc.
__global__ __launch_bounds__(256, 3) void wp_frag(
    const short* __restrict__ Afh, const short* __restrict__ Afl,
    const short* __restrict__ Bfh, const short* __restrict__ Bfl,
    float* __restrict__ C, const float* __restrict__ base,
    const float* __restrict__ colscale, int N, int K) {
  __shared__ short lds[24576];  // 48 KiB
  int bx = blockIdx.x, by = blockIdx.y;
  xcd_swizzle(bx, by, gridDim.x, gridDim.y);
  int m0 = bx * 64, n0 = by * 128;
  floatx16 acc[1][2] = {};
  gemm_frag_core<64, 128>(Afh, Afl, Bfh, Bfl, m0, n0, K, lds, acc);
  int lane = threadIdx.x & 63, wv = threadIdx.x >> 6;
  int wm = (wv >> 1) * 32, wn = (wv & 1) * 64;
  int cl = lane & 31, g2 = lane >> 5;
#pragma unroll
  for (int j = 0; j < 2; ++j) {
    int col = n0 + wn + 32 * j + cl;
    floatx16 f = acc[0][j];
    float cs = colscale ? colscale[col] : 1.f;
#pragma unroll
    for (int r = 0; r < 16; ++r) {
      int row = m0 + wm + (r & 3) + 8 * (r >> 2) + 4 * g2;
      size_t idx = (size_t)row * N + col;
      float v = f[r] * cs;
      if (base) v += base[idx];
      C[idx] = v;
    }
  }
}

// Fused q,k,v: grid (NTOK/64, 12). by<8 -> q, 8-9 -> k, 10-11 -> v (+vemb).
__global__ __launch_bounds__(256, 3) void qkv_frag(
    const short* __restrict__ xnh, const short* __restrict__ xnl,
    const short* __restrict__ wqh, const short* __restrict__ wql,
    const short* __restrict__ wkh, const short* __restrict__ wkl,
    const short* __restrict__ wvh, const short* __restrict__ wvl,
    float* __restrict__ qb, float* __restrict__ kb, float* __restrict__ vb,
    const float* __restrict__ vemb, int K) {
  __shared__ short lds[24576];  // 48 KiB
  int bx = blockIdx.x, by = blockIdx.y;
  xcd_swizzle(bx, by, gridDim.x, gridDim.y);
  const short *Bh, *Bl;
  float* C;
  const float* base = nullptr;
  int n0, ldn;
  if (by < 8) {
    Bh = wqh; Bl = wql; C = qb; n0 = by * 128; ldn = Dc;
  } else if (by < 10) {
    Bh = wkh; Bl = wkl; C = kb; n0 = (by - 8) * 128; ldn = KVDc;
  } else {
    Bh = wvh; Bl = wvl; C = vb; base = vemb; n0 = (by - 10) * 128; ldn = KVDc;
  }
  int m0 = bx * 64;
  floatx16 acc[1][2] = {};
  gemm_frag_core<64, 128>(xnh, xnl, Bh, Bl, m0, n0, K, lds, acc);
  int lane = threadIdx.x & 63, wv = threadIdx.x >> 6;
  int wm = (wv >> 1) * 32, wn = (wv & 1) * 64;
  int cl = lane & 31, g2 = lane >> 5;
#pragma unroll
  for (int j = 0; j < 2; ++j) {
    int col = n0 + wn + 32 * j + cl;
    floatx16 f = acc[0][j];
#pragma unroll
    for (int r = 0; r < 16; ++r) {
      int row = m0 + wm + (r & 3) + 8 * (r >> 2) + 4 * g2;
      size_t idx = (size_t)row * ldn + col;
      float v = f[r];
      if (base) v += base[idx];
      C[idx] = v;
    }
  }
}

// Wfc GEMM: 128x128, act=1, writes h in FRAG-ORDER planes via LDS bounce.
__global__ __launch_bounds__(256, 2) void fc_frag(
    const short* __restrict__ Afh, const short* __restrict__ Afl,
    const short* __restrict__ Bfh, const short* __restrict__ Bfl,
    short* __restrict__ Chf, short* __restrict__ Clf, int N, int K,
    int K16out) {
  __shared__ short lds[32768];  // 64 KiB (reused for epilogue bounce)
  int bx = blockIdx.x, by = blockIdx.y;
  xcd_swizzle(bx, by, gridDim.x, gridDim.y);
  int m0 = bx * 128, n0 = by * 128;
  floatx16 acc[2][2] = {};
  gemm_frag_core<128, 128>(Afh, Afl, Bfh, Bfl, m0, n0, K, lds, acc);
  int tid = threadIdx.x;
  int lane = tid & 63, wv = tid >> 6;
  int wm = (wv >> 1) * 64, wn = (wv & 1) * 64;
  int cl = lane & 31, g2 = lane >> 5;
  __syncthreads();  // LDS free; begin frag-bounce
#pragma unroll
  for (int i = 0; i < 2; ++i)
#pragma unroll
    for (int j = 0; j < 2; ++j) {
      floatx16 f = acc[i][j];
#pragma unroll
      for (int r = 0; r < 16; ++r) {
        int rowl = wm + 32 * i + (r & 3) + 8 * (r >> 2) + 4 * g2;  // 0..127
        int coll = wn + 32 * j + cl;                                // 0..127
        float v = f[r];
        float hx = (v >= 0.f) ? v : 0.5f * v;
        v = hx * hx;
        short hb = f2bf(v);
        short lb = f2bf(v - bf2f(hb));
        int sub = (rowl >> 5) * 8 + (coll >> 4);
        int lanev = (rowl & 31) + 32 * ((coll >> 3) & 1);
        int off = sub * 512 + lanev * 8 + (coll & 7);
        lds[off] = hb;
        lds[16384 + off] = lb;
      }
    }
  __syncthreads();
  size_t gbase = ((size_t)(m0 >> 5) * K16out + (n0 >> 4)) * 512;
#pragma unroll
  for (int u = 0; u < 8; ++u) {
    int idx = u * 2048 + tid * 8;
    int sub = idx >> 9, within = idx & 511;
    size_t gidx = gbase + ((size_t)(sub >> 3) * K16out + (sub & 7)) * 512 + within;
    *(short8*)(Chf + gidx) = *(const short8*)(lds + idx);
    *(short8*)(Clf + gidx) = *(const short8*)(lds + 16384 + idx);
  }
}

// ---------------------------------------------------------------------------
// QK head-RMS + RoPE (+q_gain). Block per token. (unchanged)
// ---------------------------------------------------------------------------
__global__ __launch_bounds__(256) void qkrope_kernel(
    float* __restrict__ q, float* __restrict__ k,
    const float* __restrict__ q_gain) {
  int bt = blockIdx.x;
  int t = bt % Tc;
  int tid = threadIdx.x;
  int lane = tid & 63, wv = tid >> 6;
  int fi = lane & 31;
  float inv = expf(-(float)(2 * fi) * (9.210340372f / 64.f));
  float ang = (float)t * inv;
  float cv = cosf(ang);
  float sv = sinf(ang);

#pragma unroll
  for (int hh = 0; hh < 4; ++hh) {
    int h = wv + hh * 4;
    float* qp = q + (size_t)bt * Dc + h * 64;
    float val = qp[lane];
    float ss = wave_sum(val * val);
    float rn = rsqrtf(ss / 64.f + 1e-6f);
    val *= rn;
    float partner = __shfl(val, lane ^ 32);
    float out = (lane < 32) ? (val * cv + partner * sv) : (val * cv - partner * sv);
    out *= q_gain[h];
    qp[lane] = out;
  }
  {
    int h = wv;
    float* kp = k + (size_t)bt * KVDc + h * 64;
    float val = kp[lane];
    float ss = wave_sum(val * val);
    float rn = rsqrtf(ss / 64.f + 1e-6f);
    val *= rn;
    float partner = __shfl(val, lane ^ 32);
    float out = (lane < 32) ? (val * cv + partner * sv) : (val * cv - partner * sv);
    kp[lane] = out;
  }
}

// ---------------------------------------------------------------------------
// K/V^T frag-order plane prep (unchanged).
// ---------------------------------------------------------------------------
__global__ __launch_bounds__(256) void kvprep_kernel(
    const float* __restrict__ kb, const float* __restrict__ vb,
    short* __restrict__ khG, short* __restrict__ klG,
    short* __restrict__ vthG, short* __restrict__ vtlG) {
  __shared__ float kf[64][65];
  __shared__ float vf[64][65];
  int kt = blockIdx.x, bh = blockIdx.y;
  int b = bh >> 2, hkv = bh & 3;
  int tid = threadIdx.x;
#pragma unroll
  for (int u = 0; u < 4; ++u) {
    int idx = tid + u * 256;
    int row = idx >> 4, c4 = idx & 15;
    size_t off = ((size_t)(b * Tc + kt * 64 + row)) * KVDc + hkv * 64 + c4 * 4;
    float4 k4 = *(const float4*)(kb + off);
    float4 v4 = *(const float4*)(vb + off);
    kf[row][c4 * 4 + 0] = k4.x; kf[row][c4 * 4 + 1] = k4.y;
    kf[row][c4 * 4 + 2] = k4.z; kf[row][c4 * 4 + 3] = k4.w;
    vf[row][c4 * 4 + 0] = v4.x; vf[row][c4 * 4 + 1] = v4.y;
    vf[row][c4 * 4 + 2] = v4.z; vf[row][c4 * 4 + 3] = v4.w;
  }
  __syncthreads();
  size_t gb = ((size_t)(bh * (Tc / 64) + kt)) * 4096;
#pragma unroll
  for (int u = 0; u < 2; ++u) {
    int unit = tid + u * 256;
    int s = unit >> 6, p = unit & 63;
    {
      int half = s >> 2, rg = s & 3;
      int row = rg * 16 + (p & 15);
      int d0 = half * 32 + (p >> 4) * 8;
      short8 h8, l8;
#pragma unroll
      for (int e = 0; e < 8; ++e) {
        float v = kf[row][d0 + e];
        short hb = f2bf(v);
        h8[e] = hb;
        l8[e] = f2bf(v - bf2f(hb));
      }
      *(short8*)(khG + gb + s * 512 + p * 8) = h8;
      *(short8*)(klG + gb + s * 512 + p * 8) = l8;
    }
    {
      int ks = s >> 2, jd = s & 3;
      int d = jd * 16 + (p & 15);
      int k0 = ks * 32 + (p >> 4) * 8;
      short8 h8, l8;
#pragma unroll
      for (int e = 0; e < 8; ++e) {
        float v = vf[k0 + e][d];
        short hb = f2bf(v);
        h8[e] = hb;
        l8[e] = f2bf(v - bf2f(hb));
      }
      *(short8*)(vthG + gb + s * 512 + p * 8) = h8;
      *(short8*)(vtlG + gb + s * 512 + p * 8) = l8;
    }
  }
}

// ---------------------------------------------------------------------------
// MFMA causal GQA flash attention + v-direction-removal epilogue.
// y output written directly in FRAG-ORDER planes (consumed by wp_frag).
// ---------------------------------------------------------------------------
__global__ __launch_bounds__(256) void attn_mfma(
    const float* __restrict__ qg_, const float* __restrict__ vg_,
    const short* __restrict__ khG, const short* __restrict__ klG,
    const short* __restrict__ vthG, const short* __restrict__ vtlG,
    short* __restrict__ yh_, short* __restrict__ yl_) {
  __shared__ short smem[24576];  // 48 KiB
  short* Khi  = smem;
  short* Klo  = smem + 4096;
  short* Vthi = smem + 8192;
  short* Vtlo = smem + 12288;

  int bh = blockIdx.x;
  int qt = (gridDim.y - 1) - blockIdx.y;
  int b = bh >> 2, hkv = bh & 3;
  int tid = threadIdx.x;
  int lane = tid & 63, wv = tid >> 6;
  int x = lane & 15, g = lane >> 4;
  int h = hkv * 4 + wv;
  int qbase = qt * 16;

  short* PAhi = smem + 16384 + wv * 1024;
  short* PAlo = smem + 20480 + wv * 1024;

  short8 qh[2], qlo[2];
#pragma unroll
  for (int ks = 0; ks < 2; ++ks) {
    int qrow = qbase + x;
    const float* qp =
        qg_ + ((size_t)(b * Tc + qrow)) * Dc + h * 64 + ks * 32 + g * 8;
    float4 f0 = *(const float4*)qp;
    float4 f1 = *(const float4*)(qp + 4);
    float fv[8] = {f0.x, f0.y, f0.z, f0.w, f1.x, f1.y, f1.z, f1.w};
#pragma unroll
    for (int e = 0; e < 8; ++e) {
      short hb = f2bf(fv[e]);
      qh[ks][e] = hb;
      qlo[ks][e] = f2bf(fv[e] - bf2f(hb));
    }
  }

  const short* planes[4] = {khG, klG, vthG, vtlG};
  const short* gplane = planes[wv] + ((size_t)bh * (Tc / 64)) * 4096 + lane * 8;
  short* lplane = smem + wv * 4096;

  floatx4 o[4] = {};
  float m_run = NEG_BIG, l_run = 0.f;

  int nkt = (qbase >> 6) + 1;
  for (int kt = 0; kt < nkt; ++kt) {
    const short* gs = gplane + (size_t)kt * 4096;
#pragma unroll
    for (int t = 0; t < 8; ++t) gll16(gs + t * 512, lplane + t * 512);
    __syncthreads();

    floatx4 st[4] = {};
#pragma unroll
    for (int ks = 0; ks < 2; ++ks) {
#pragma unroll
      for (int i = 0; i < 4; ++i) {
        short8 ka_h = *(const short8*)(Khi + ks * 2048 + i * 512 + lane * 8);
        short8 ka_l = *(const short8*)(Klo + ks * 2048 + i * 512 + lane * 8);
        st[i] = __builtin_amdgcn_mfma_f32_16x16x32_bf16(ka_h, qh[ks], st[i], 0, 0, 0);
        st[i] = __builtin_amdgcn_mfma_f32_16x16x32_bf16(ka_h, qlo[ks], st[i], 0, 0, 0);
        st[i] = __builtin_amdgcn_mfma_f32_16x16x32_bf16(ka_l, qh[ks], st[i], 0, 0, 0);
      }
    }

    float alv;
    {
      int qrow = qbase + x;
      float mx = NEG_BIG;
#pragma unroll
      for (int i = 0; i < 4; ++i) {
#pragma unroll
        for (int r = 0; r < 4; ++r) {
          int krow = kt * 64 + 16 * i + 4 * g + r;
          float s = st[i][r] * 0.125f;
          if (krow > qrow) s = NEG_BIG;
          st[i][r] = s;
          mx = fmaxf(mx, s);
        }
      }
      mx = fmaxf(mx, __shfl_xor(mx, 16));
      mx = fmaxf(mx, __shfl_xor(mx, 32));
      float m_new = fmaxf(m_run, mx);
      alv = __expf(m_run - m_new);
      float ts = 0.f;
#pragma unroll
      for (int i = 0; i < 4; ++i) {
#pragma unroll
        for (int r = 0; r < 4; ++r) {
          float p = __expf(st[i][r] - m_new);
          st[i][r] = p;
          ts += p;
        }
      }
      ts += __shfl_xor(ts, 16);
      ts += __shfl_xor(ts, 32);
      l_run = l_run * alv + ts;
      m_run = m_new;
    }

#pragma unroll
    for (int i = 0; i < 4; ++i) {
      short4v h4, l4;
#pragma unroll
      for (int r = 0; r < 4; ++r) {
        float p = st[i][r];
        short hb = f2bf(p);
        h4[r] = hb;
        l4[r] = f2bf(p - bf2f(hb));
      }
      int offp = (i >> 1) * 512 +
                 (x + (2 * (i & 1) + (g >> 1)) * 16) * 8 + 4 * (g & 1);
      *(short4v*)(PAhi + offp) = h4;
      *(short4v*)(PAlo + offp) = l4;
    }

#pragma unroll
    for (int r = 0; r < 4; ++r) {
      float a = __shfl(alv, 4 * g + r);
#pragma unroll
      for (int jd = 0; jd < 4; ++jd) o[jd][r] *= a;
    }
    __syncthreads();

#pragma unroll
    for (int ks = 0; ks < 2; ++ks) {
      short8 pa_h = *(const short8*)(PAhi + ks * 512 + lane * 8);
      short8 pa_l = *(const short8*)(PAlo + ks * 512 + lane * 8);
#pragma unroll
      for (int jd = 0; jd < 4; ++jd) {
        short8 vb_h = *(const short8*)(Vthi + ks * 2048 + jd * 512 + lane * 8);
        short8 vb_l = *(const short8*)(Vtlo + ks * 2048 + jd * 512 + lane * 8);
        o[jd] = __builtin_amdgcn_mfma_f32_16x16x32_bf16(pa_h, vb_h, o[jd], 0, 0, 0);
        o[jd] = __builtin_amdgcn_mfma_f32_16x16x32_bf16(pa_h, vb_l, o[jd], 0, 0, 0);
        o[jd] = __builtin_amdgcn_mfma_f32_16x16x32_bf16(pa_l, vb_h, o[jd], 0, 0, 0);
      }
    }
    __syncthreads();
  }

  // finalize: /l_run, remove v-component, store y in FRAG-ORDER planes.
#pragma unroll
  for (int r = 0; r < 4; ++r) {
    float lr = __shfl(l_run, 4 * g + r);
    float rcp = 1.f / lr;
    int qrow = qbase + 4 * g + r;
    const float* vr = vg_ + ((size_t)(b * Tc + qrow)) * KVDc + hkv * 64;
    float vv[4], oo[4];
    float pn = 0.f, pd = 0.f;
#pragma unroll
    for (int jd = 0; jd < 4; ++jd) {
      vv[jd] = vr[16 * jd + x];
      oo[jd] = o[jd][r] * rcp;
      pn += vv[jd] * vv[jd];
      pd += oo[jd] * vv[jd];
    }
#pragma unroll
    for (int off = 1; off <= 8; off <<= 1) {
      pn += __shfl_xor(pn, off);
      pd += __shfl_xor(pd, off);
    }
    float nrm = sqrtf(pn);
    float mxv = fmaxf(nrm, 1e-12f);
    float si = 1.f / mxv;
    float co = pd * si * si;
    int grow = b * Tc + qrow;
    size_t fb = ((size_t)(grow >> 5)) * 64 * 512 +
                ((size_t)(grow & 31) + 32 * (x >> 3)) * 8 + (x & 7);
#pragma unroll
    for (int jd = 0; jd < 4; ++jd) {
      float val = oo[jd] - co * vv[jd];
      short hb = f2bf(val);
      size_t off = fb + (size_t)(h * 4 + jd) * 512;
      yh_[off] = hb;
      yl_[off] = f2bf(val - bf2f(hb));
    }
  }
}

// ---------------------------------------------------------------------------
extern "C" void kernel_launch(void* const* d_in, const int* in_sizes, int n_in,
                              void* d_out, int out_size, void* d_ws,
                              size_t ws_size, hipStream_t stream) {
  const int* ids          = (const int*)d_in[0];
  const float* embed_w    = (const float*)d_in[1];
  const float* big_w      = (const float*)d_in[2];
  const float* big_proj   = (const float*)d_in[3];
  const float* big_scale  = (const float*)d_in[4];
  const float* smear_gate = (const float*)d_in[5];
  const float* ve_w       = (const float*)d_in[6];
  const float* ve_proj    = (const float*)d_in[7];
  const float* ve_scale   = (const float*)d_in[8];
  const float* Wq         = (const float*)d_in[9];
  const float* Wk         = (const float*)d_in[10];
  const float* Wv         = (const float*)d_in[11];
  const float* Wo         = (const float*)d_in[12];
  const float* q_gain     = (const float*)d_in[13];
  const float* attn_scale = (const float*)d_in[14];
  const float* mlp_scale  = (const float*)d_in[15];
  const float* resid_mix  = (const float*)d_in[16];
  const float* Wfc        = (const float*)d_in[17];
  const float* Wp         = (const float*)d_in[18];
  const float* head_w     = (const float*)d_in[19];
  float* out = (float*)d_out;

  // ---- workspace layout ----
  char* p = (char*)d_ws;
  float* x     = (float*)p; p += SZ_X * 4;
  float* x0    = (float*)p; p += SZ_X * 4;
  float* x_in  = (float*)p; p += SZ_X * 4;
  float* qb    = (float*)p; p += SZ_X * 4;
  float* kb    = (float*)p; p += SZ_KV * 4;
  float* vb    = (float*)p; p += SZ_KV * 4;
  float* vemb  = (float*)p; p += SZ_KV * 4;
  float* raw_x = (float*)p; p += SZ_X * 4;
  short* xnh = (short*)p; p += SZ_X * 2;   // frag-order
  short* xnl = (short*)p; p += SZ_X * 2;
  short* yh  = (short*)p; p += SZ_X * 2;   // frag-order
  short* yl  = (short*)p; p += SZ_X * 2;
  short* hh  = (short*)p; p += SZ_H * 2;   // frag-order
  short* hl  = (short*)p; p += SZ_H * 2;
  short* khG  = (short*)p; p += SZ_KVP * 2;
  short* klG  = (short*)p; p += SZ_KVP * 2;
  short* vthG = (short*)p; p += SZ_KVP * 2;
  short* vtlG = (short*)p; p += SZ_KVP * 2;
  short* wqh = (short*)p; p += W_Q * 2;
  short* wql = (short*)p; p += W_Q * 2;
  short* wkh = (short*)p; p += W_KV * 2;
  short* wkl = (short*)p; p += W_KV * 2;
  short* wvh = (short*)p; p += W_KV * 2;
  short* wvl = (short*)p; p += W_KV * 2;
  short* woh = (short*)p; p += W_Q * 2;
  short* wol = (short*)p; p += W_Q * 2;
  short* wfh = (short*)p; p += W_FC * 2;
  short* wfl = (short*)p; p += W_FC * 2;
  short* wph = (short*)p; p += W_FC * 2;
  short* wpl = (short*)p; p += W_FC * 2;
  short* hwh = (short*)p; p += W_HD * 2;
  short* hwl = (short*)p; p += W_HD * 2;

  // ---- weight conversion: BATCHED over all layers (7 launches total).
  auto wcf = [&](const float* s, short* h, short* l2, int N, int Npad, int K) {
    long n8 = (long)Npad * (K >> 3);
    int blocks = (int)((n8 + 255) / 256);
    wcvt_frag_kernel<<<blocks, 256, 0, stream>>>(s, h, l2, N, Npad, K);
  };
  wcf(Wq, wqh, wql, Lc * Dc, Lc * Dc, Dc);
  wcf(Wk, wkh, wkl, Lc * KVDc, Lc * KVDc, Dc);
  wcf(Wv, wvh, wvl, Lc * KVDc, Lc * KVDc, Dc);
  wcf(Wo, woh, wol, Lc * Dc, Lc * Dc, Dc);
  wcf(Wfc, wfh, wfl, Lc * MLPc, Lc * MLPc, Dc);
  wcf(Wp, wph, wpl, Lc * Dc, Lc * Dc, MLPc);
  wcf(head_w, hwh, hwl, Vc, VPAD, Dc);

  embed_kernel<<<NTOK, 256, 0, stream>>>(ids, embed_w, big_w, big_proj,
                                         big_scale, ve_w, ve_proj, ve_scale,
                                         raw_x, vemb);
  smear_kernel<<<(int)(SZ_X / 256), 256, 0, stream>>>(raw_x, smear_gate, x, x0);

  for (int l = 0; l < Lc; ++l) {
    const float* mix = resid_mix + (size_t)l * 2 * Dc;
    prelayer_kernel<<<NTOK, 256, 0, stream>>>(x, x0, mix, x_in, xnh, xnl);
    qkv_frag<<<dim3(NTOK / 64, 12), 256, 0, stream>>>(
        xnh, xnl, wqh + (size_t)l * Dc * Dc, wql + (size_t)l * Dc * Dc,
        wkh + (size_t)l * KVDc * Dc, wkl + (size_t)l * KVDc * Dc,
        wvh + (size_t)l * KVDc * Dc, wvl + (size_t)l * KVDc * Dc, qb, kb, vb,
        vemb, Dc);
    qkrope_kernel<<<NTOK, 256, 0, stream>>>(qb, kb, q_gain + (size_t)l * Hc);
    kvprep_kernel<<<dim3(Tc / 64, Bc * HKVc), 256, 0, stream>>>(
        kb, vb, khG, klG, vthG, vtlG);
    attn_mfma<<<dim3(Bc * HKVc, Tc / 16), 256, 0, stream>>>(
        qb, vb, khG, klG, vthG, vtlG, yh, yl);
    // out proj + residual: x = x_in + attn_scale * (y @ Wo.T)
    wp_frag<<<dim3(NTOK / 64, Dc / 128), 256, 0, stream>>>(
        yh, yl, woh + (size_t)l * Dc * Dc, wol + (size_t)l * Dc * Dc, x, x_in,
        attn_scale + (size_t)l * Dc, Dc, Dc);
    // MLP
    rms_split_kernel<<<NTOK, 256, 0, stream>>>(x, xnh, xnl);
    fc_frag<<<dim3(NTOK / 128, MLPc / 128), 256, 0, stream>>>(
        xnh, xnl, wfh + (size_t)l * MLPc * Dc, wfl + (size_t)l * MLPc * Dc, hh,
        hl, MLPc, Dc, MLPc >> 4);
    wp_frag<<<dim3(NTOK / 64, Dc / 128), 256, 0, stream>>>(
        hh, hl, wph + (size_t)l * Dc * MLPc, wpl + (size_t)l * Dc * MLPc, x, x,
        mlp_scale + (size_t)l * Dc, Dc, MLPc);
  }

  rms_split_kernel<<<NTOK, 256, 0, stream>>>(x, xnh, xnl);
  head_frag<<<dim3(NTOK / 128, VPAD / 128), 256, 0, stream>>>(
      xnh, xnl, hwh, hwl, out, Vc, Dc);
}

// Round 14
// 4169.965 us; speedup vs baseline: 1.0376x; 1.0267x over previous
//
#include <hip/hip_runtime.h>
#include <hip/hip_bf16.h>

// Problem constants (match reference)
constexpr int Bc   = 2;
constexpr int Tc   = 1024;
constexpr int Vc   = 50257;
constexpr int Lc   = 8;
constexpr int Dc   = 1024;
constexpr int Hc   = 16;
constexpr int HKVc = 4;
constexpr int HDc  = 64;     // D/H
constexpr int KVDc = 256;    // HKV*HD
constexpr int MLPc = 4096;   // 4*D
constexpr int BVc  = 65536;
constexpr int BDc  = 256;
constexpr int VEDc = 128;

constexpr int NTOK = Bc * Tc;          // 2048
constexpr long SZ_X  = (long)NTOK * Dc;    // 2,097,152
constexpr long SZ_KV = (long)NTOK * KVDc;  // 524,288
constexpr long SZ_H  = (long)NTOK * MLPc;  // 8,388,608

constexpr int  VPAD = 50432;                  // Vc padded to 256
constexpr long W_Q  = (long)Lc * Dc * Dc;     // 8,388,608
constexpr long W_KV = (long)Lc * KVDc * Dc;   // 2,097,152
constexpr long W_FC = (long)Lc * MLPc * Dc;   // 33,554,432
constexpr long W_HD = (long)VPAD * Dc;        // frag-order, padded
constexpr long SZ_KVP = (long)Bc * HKVc * (Tc / 64) * 4096;  // shorts/plane

#define NEG_BIG (-3.0e38f)

typedef __attribute__((ext_vector_type(8))) short short8;    // 8 bf16 (4 VGPRs)
typedef __attribute__((ext_vector_type(4))) short short4v;   // 4 bf16 (8 B)
typedef __attribute__((ext_vector_type(4))) float floatx4;   // 16x16 MFMA acc
typedef __attribute__((ext_vector_type(16))) float floatx16; // 32x32 MFMA acc

__device__ __forceinline__ float wave_sum(float v) {
#pragma unroll
  for (int off = 32; off >= 1; off >>= 1) v += __shfl_xor(v, off);
  return v;
}

// Bijective XCD-aware swizzle (m204 formula).
__device__ __forceinline__ void xcd_swizzle(int& bx, int& by, int nbx, int nby) {
  int n = nbx * nby;
  int lin = by * nbx + bx;
  int q = n >> 3, rm = n & 7;
  int xcd = lin & 7, idx = lin >> 3;
  int v = (xcd < rm) ? (xcd * (q + 1) + idx)
                     : (rm * (q + 1) + (xcd - rm) * q + idx);
  bx = v % nbx;
  by = v / nbx;
}

// async global->LDS, 16B per lane. LDS dest = wave-uniform base + lane*16.
__device__ __forceinline__ void gll16(const void* g, void* l) {
  __builtin_amdgcn_global_load_lds(
      (const __attribute__((address_space(1))) unsigned int*)g,
      (__attribute__((address_space(3))) unsigned int*)l, 16, 0, 0);
}

// ---------------------------------------------------------------------------
// bf16 split helpers: f = bf2f(hi) + bf2f(lo) + O(2^-17 * f)
// ---------------------------------------------------------------------------
__device__ __forceinline__ short f2bf(float f) {
  unsigned u = __float_as_uint(f);
  return (short)((u + 0x7fffu + ((u >> 16) & 1u)) >> 16);
}
__device__ __forceinline__ float bf2f(short h) {
  return __uint_as_float(((unsigned)(unsigned short)h) << 16);
}

// ---------------------------------------------------------------------------
// Weight conversion: fp32 row-major [N][K] -> frag-order hi/lo planes
//   layout [Npad/32][K/16][64 lanes][8 shorts]; lane = (r&31) + 32*(k8&1).
// Layer-contiguous: batched over all layers in ONE launch.
// ---------------------------------------------------------------------------
__global__ __launch_bounds__(256) void wcvt_frag_kernel(
    const float* __restrict__ src, short* __restrict__ hi,
    short* __restrict__ lo, int N, int Npad, int K) {
  long i = (long)blockIdx.x * 256 + threadIdx.x;
  int K8 = K >> 3;
  long n8 = (long)Npad * K8;
  if (i >= n8) return;
  int r = (int)(i / K8);
  int k8 = (int)(i % K8);
  float fv[8] = {};
  if (r < N) {
    const float* s = src + (size_t)r * K + k8 * 8;
    float4 f0 = *(const float4*)s;
    float4 f1 = *(const float4*)(s + 4);
    fv[0] = f0.x; fv[1] = f0.y; fv[2] = f0.z; fv[3] = f0.w;
    fv[4] = f1.x; fv[5] = f1.y; fv[6] = f1.z; fv[7] = f1.w;
  }
  short8 h8, l8;
#pragma unroll
  for (int e = 0; e < 8; ++e) {
    short hb = f2bf(fv[e]);
    h8[e] = hb;
    l8[e] = f2bf(fv[e] - bf2f(hb));
  }
  int rg = r >> 5, ksi = k8 >> 1;
  int lanev = (r & 31) + ((k8 & 1) << 5);
  size_t off = (((size_t)rg * (K >> 4) + ksi) * 64 + lanev) * 8;
  *(short8*)(hi + off) = h8;
  *(short8*)(lo + off) = l8;
}

// ---------------------------------------------------------------------------
// Embedding (unchanged)
// ---------------------------------------------------------------------------
__global__ __launch_bounds__(256) void embed_kernel(
    const int* __restrict__ ids, const float* __restrict__ embed_w,
    const float* __restrict__ big_w, const float* __restrict__ big_proj,
    const float* __restrict__ big_scale, const float* __restrict__ ve_w,
    const float* __restrict__ ve_proj, const float* __restrict__ ve_scale,
    float* __restrict__ raw_x, float* __restrict__ vemb) {
  int bt = blockIdx.x;
  int tid = threadIdx.x;
  int t = bt % Tc;
  int tok = ids[bt];

  const float* e = embed_w + (size_t)tok * Dc;
  float ev[4];
  float ss = 0.f;
#pragma unroll
  for (int i = 0; i < 4; ++i) {
    ev[i] = e[tid + i * 256];
    ss += ev[i] * ev[i];
  }
  __shared__ float red[4];
  __shared__ float brow[BDc];
  __shared__ float verow[VEDc];
  float wsum = wave_sum(ss);
  if ((tid & 63) == 0) red[tid >> 6] = wsum;

  int bg;
  if (t == 0) {
    bg = BVc - 1;
  } else {
    unsigned a = (unsigned)ids[bt];
    unsigned p = (unsigned)ids[bt - 1];
    bg = (int)(((36313u * a) ^ (27191u * p)) % 65535u);
  }
  brow[tid] = big_w[(size_t)bg * BDc + tid];
  if (tid < VEDc) verow[tid] = ve_w[(size_t)tok * VEDc + tid];
  __syncthreads();

  float tot = red[0] + red[1] + red[2] + red[3];
  float rn = rsqrtf(tot / (float)Dc + 1e-6f);
  float bs = big_scale[0];
#pragma unroll
  for (int i = 0; i < 4; ++i) {
    int d = tid + i * 256;
    const float* bp = big_proj + (size_t)d * BDc;
    float dot = 0.f;
    for (int c = 0; c < BDc; ++c) dot += brow[c] * bp[c];
    raw_x[(size_t)bt * Dc + d] = ev[i] * rn + dot * bs;
  }
  {
    float vs = ve_scale[0];
    int d = tid;
    const float* vp = ve_proj + (size_t)d * VEDc;
    float dot = 0.f;
    for (int c = 0; c < VEDc; ++c) dot += verow[c] * vp[c];
    vemb[(size_t)bt * KVDc + d] = dot * vs;
  }
}

// ---------------------------------------------------------------------------
// Smear (unchanged)
// ---------------------------------------------------------------------------
__global__ __launch_bounds__(256) void smear_kernel(
    const float* __restrict__ raw, const float* __restrict__ gate,
    float* __restrict__ x, float* __restrict__ x0) {
  long idx = (long)blockIdx.x * 256 + threadIdx.x;
  if (idx >= SZ_X) return;
  int d = (int)(idx & (Dc - 1));
  int t = (int)((idx / Dc) & (Tc - 1));
  float g = 1.f / (1.f + expf(-gate[d]));
  float cur = raw[idx];
  float prev = (t > 0) ? raw[idx - Dc] : 0.f;
  float val = (1.f - g) * cur + g * prev;
  x[idx] = val;
  x0[idx] = val;
}

// ---------------------------------------------------------------------------
// frag-order activation store: token bt, 4 consecutive elems at d0=4*tid.
// ---------------------------------------------------------------------------
__device__ __forceinline__ void store_frag4(short* __restrict__ ph,
                                            short* __restrict__ pl, int bt,
                                            int d0, int K16, const float* v) {
  short4v h4, l4;
#pragma unroll
  for (int e = 0; e < 4; ++e) {
    short hb = f2bf(v[e]);
    h4[e] = hb;
    l4[e] = f2bf(v[e] - bf2f(hb));
  }
  int lanev = (bt & 31) + 32 * ((d0 >> 3) & 1);
  size_t off = (((size_t)(bt >> 5) * K16 + (d0 >> 4)) * 64 + lanev) * 8 + (d0 & 7);
  *(short4v*)(ph + off) = h4;
  *(short4v*)(pl + off) = l4;
}

// ---------------------------------------------------------------------------
// Pre-layer: x_in = mix0*x + mix1*x0 ; xn frag planes = split(rms(x_in)).
// ---------------------------------------------------------------------------
__global__ __launch_bounds__(256) void prelayer_kernel(
    const float* __restrict__ x, const float* __restrict__ x0,
    const float* __restrict__ mix, float* __restrict__ x_in,
    short* __restrict__ xnh, short* __restrict__ xnl) {
  int bt = blockIdx.x;
  int tid = threadIdx.x;
  int d0 = tid * 4;
  const float* xr = x + (size_t)bt * Dc;
  const float* x0r = x0 + (size_t)bt * Dc;
  float4 xv = *(const float4*)(xr + d0);
  float4 x0v = *(const float4*)(x0r + d0);
  float4 m0 = *(const float4*)(mix + d0);
  float4 m1 = *(const float4*)(mix + Dc + d0);
  float vals[4] = {m0.x * xv.x + m1.x * x0v.x, m0.y * xv.y + m1.y * x0v.y,
                   m0.z * xv.z + m1.z * x0v.z, m0.w * xv.w + m1.w * x0v.w};
  float ss = vals[0] * vals[0] + vals[1] * vals[1] + vals[2] * vals[2] +
             vals[3] * vals[3];
  __shared__ float red[4];
  float wsum = wave_sum(ss);
  if ((tid & 63) == 0) red[tid >> 6] = wsum;
  __syncthreads();
  float tot = red[0] + red[1] + red[2] + red[3];
  float rn = rsqrtf(tot / (float)Dc + 1e-6f);
  *(float4*)(x_in + (size_t)bt * Dc + d0) =
      make_float4(vals[0], vals[1], vals[2], vals[3]);
  float vn[4] = {vals[0] * rn, vals[1] * rn, vals[2] * rn, vals[3] * rn};
  store_frag4(xnh, xnl, bt, d0, Dc >> 4, vn);
}

// ---------------------------------------------------------------------------
// RMS over D -> frag-order bf16 hi/lo planes. Block per token.
// ---------------------------------------------------------------------------
__global__ __launch_bounds__(256) void rms_split_kernel(
    const float* __restrict__ in, short* __restrict__ oh,
    short* __restrict__ ol) {
  int bt = blockIdx.x;
  int tid = threadIdx.x;
  int d0 = tid * 4;
  float4 v4 = *(const float4*)(in + (size_t)bt * Dc + d0);
  float v[4] = {v4.x, v4.y, v4.z, v4.w};
  float ss = v[0] * v[0] + v[1] * v[1] + v[2] * v[2] + v[3] * v[3];
  __shared__ float red[4];
  float wsum = wave_sum(ss);
  if ((tid & 63) == 0) red[tid >> 6] = wsum;
  __syncthreads();
  float tot = red[0] + red[1] + red[2] + red[3];
  float rn = rsqrtf(tot / (float)Dc + 1e-6f);
  float vn[4] = {v[0] * rn, v[1] * rn, v[2] * rn, v[3] * rn};
  store_frag4(oh, ol, bt, d0, Dc >> 4, vn);
}

// ---------------------------------------------------------------------------
// Frag-order GEMM core (R9/R11 structure; best verified at ~50% MfmaUtil).
// A and B BOTH in frag-order global planes [R/32][K/16][64][8]; every
// global_load_lds is ONE contiguous 1KB packet. Counted-vmcnt double-buffered
// pipeline. 2 blocks/CU give the 2-waves/SIMD overlap (R12 lesson).
// ---------------------------------------------------------------------------
template <int BM, int BN>
__device__ __forceinline__ void gemm_frag_core(
    const short* __restrict__ Afh, const short* __restrict__ Afl,
    const short* __restrict__ Bfh, const short* __restrict__ Bfl, int m0,
    int n0, int K, short* lds, floatx16 (*acc)[BN / 64]) {
  constexpr int RGA = BM / 32;
  constexpr int RGB = BN / 32;
  constexpr int SPW = RGA + RGB;        // gll16 per wave per tile
  constexpr int PLA = RGA * 1024;
  constexpr int PLB = RGB * 1024;
  constexpr int HB = 2 * (PLA + PLB);   // shorts per buffer
  constexpr int FI = BM / 64;
  constexpr int FJ = BN / 64;

  int tid = threadIdx.x, lane = tid & 63, wv = tid >> 6;
  int K16 = K >> 4;

  const short* gsrc[SPW];
  int ldst[SPW];
#pragma unroll
  for (int t = 0; t < SPW; ++t) {
    int s = wv * SPW + t;
    const short* plane;
    int poff, rg, ks;
    size_t base;
    if (s < RGA * 4) {
      int p = s / (RGA * 2);
      int rem = s % (RGA * 2);
      rg = rem >> 1; ks = rem & 1;
      plane = p ? Afl : Afh;
      poff = p ? PLA : 0;
      base = (((size_t)(m0 >> 5) + rg) * K16 + ks) * 512;
    } else {
      int s2 = s - RGA * 4;
      int p = s2 / (RGB * 2);
      int rem = s2 % (RGB * 2);
      rg = rem >> 1; ks = rem & 1;
      plane = p ? Bfl : Bfh;
      poff = 2 * PLA + (p ? PLB : 0);
      base = (((size_t)(n0 >> 5) + rg) * K16 + ks) * 512;
    }
    gsrc[t] = plane + base + lane * 8;
    ldst[t] = poff + (rg * 2 + ks) * 512;
  }

  int wm = (wv >> 1) * (BM / 2), wn = (wv & 1) * (BN / 2);

  // prologue: tile 0 -> buf0, tile 1 -> buf1 (K >= 64 everywhere here)
#pragma unroll
  for (int t = 0; t < SPW; ++t) gll16(gsrc[t], lds + ldst[t]);
#pragma unroll
  for (int t = 0; t < SPW; ++t) gsrc[t] += 1024;
#pragma unroll
  for (int t = 0; t < SPW; ++t) gll16(gsrc[t], lds + HB + ldst[t]);
#pragma unroll
  for (int t = 0; t < SPW; ++t) gsrc[t] += 1024;

  int cur = 0;
  for (int k0 = 0; k0 < K; k0 += 32) {
    if (k0 + 32 < K) {
      if constexpr (SPW == 8) {
        asm volatile("s_waitcnt vmcnt(8)" ::: "memory");
      } else {
        asm volatile("s_waitcnt vmcnt(6)" ::: "memory");
      }
    } else {
      asm volatile("s_waitcnt vmcnt(0)" ::: "memory");
    }
    __builtin_amdgcn_s_barrier();
    __builtin_amdgcn_sched_barrier(0);

    const short* As_h = lds + cur * HB;
    const short* As_l = As_h + PLA;
    const short* Bs_h = As_h + 2 * PLA;
    const short* Bs_l = Bs_h + PLB;
    short8 ah[2][FI], alx[2][FI], bhx[2][FJ], blx[2][FJ];
#pragma unroll
    for (int ks = 0; ks < 2; ++ks) {
#pragma unroll
      for (int i = 0; i < FI; ++i) {
        int rg = (wm >> 5) + i;
        ah[ks][i]  = *(const short8*)(As_h + (rg * 2 + ks) * 512 + lane * 8);
        alx[ks][i] = *(const short8*)(As_l + (rg * 2 + ks) * 512 + lane * 8);
      }
#pragma unroll
      for (int j = 0; j < FJ; ++j) {
        int rg = (wn >> 5) + j;
        bhx[ks][j] = *(const short8*)(Bs_h + (rg * 2 + ks) * 512 + lane * 8);
        blx[ks][j] = *(const short8*)(Bs_l + (rg * 2 + ks) * 512 + lane * 8);
      }
    }
    asm volatile("s_waitcnt lgkmcnt(0)" ::: "memory");
    __builtin_amdgcn_sched_barrier(0);
    __builtin_amdgcn_s_barrier();  // all waves done reading buf[cur]

    if (k0 + 64 < K) {  // stage tile k+2 into freed buffer
#pragma unroll
      for (int t = 0; t < SPW; ++t) gll16(gsrc[t], lds + cur * HB + ldst[t]);
#pragma unroll
      for (int t = 0; t < SPW; ++t) gsrc[t] += 1024;
    }
    __builtin_amdgcn_sched_barrier(0);

    __builtin_amdgcn_s_setprio(1);
#pragma unroll
    for (int ks = 0; ks < 2; ++ks) {
#pragma unroll
      for (int i = 0; i < FI; ++i)
#pragma unroll
        for (int j = 0; j < FJ; ++j)
          acc[i][j] = __builtin_amdgcn_mfma_f32_32x32x16_bf16(ah[ks][i], bhx[ks][j], acc[i][j], 0, 0, 0);
#pragma unroll
      for (int i = 0; i < FI; ++i)
#pragma unroll
        for (int j = 0; j < FJ; ++j)
          acc[i][j] = __builtin_amdgcn_mfma_f32_32x32x16_bf16(ah[ks][i], blx[ks][j], acc[i][j], 0, 0, 0);
#pragma unroll
      for (int i = 0; i < FI; ++i)
#pragma unroll
        for (int j = 0; j < FJ; ++j)
          acc[i][j] = __builtin_amdgcn_mfma_f32_32x32x16_bf16(alx[ks][i], bhx[ks][j], acc[i][j], 0, 0, 0);
    }
    __builtin_amdgcn_s_setprio(0);
    cur ^= 1;
  }
}

// head GEMM: 128x128, fp32 C with column guard.
__global__ __launch_bounds__(256, 2) void head_frag(
    const short* __restrict__ Afh, const short* __restrict__ Afl,
    const short* __restrict__ Bfh, const short* __restrict__ Bfl,
    float* __restrict__ C, int N, int K) {
  __shared__ short lds[32768];  // 64 KiB
  int bx = blockIdx.x, by = blockIdx.y;
  xcd_swizzle(bx, by, gridDim.x, gridDim.y);
  int m0 = bx * 128, n0 = by * 128;
  floatx16 acc[2][2] = {};
  gemm_frag_core<128, 128>(Afh, Afl, Bfh, Bfl, m0, n0, K, lds, acc);
  int lane = threadIdx.x & 63, wv = threadIdx.x >> 6;
  int wm = (wv >> 1) * 64, wn = (wv & 1) * 64;
  int cl = lane & 31, g2 = lane >> 5;
#pragma unroll
  for (int i = 0; i < 2; ++i)
#pragma unroll
    for (int j = 0; j < 2; ++j) {
      int col = n0 + wn + 32 * j + cl;
      if (col >= N) continue;
      floatx16 f = acc[i][j];
#pragma unroll
      for (int r = 0; r < 16; ++r) {
        int row = m0 + wm + 32 * i + (r & 3) + 8 * (r >> 2) + 4 * g2;
        C[(size_t)row * N + col] = f[r];
      }
    }
}

// Wp GEMM: 64x128, fp32 C = base + colscale * acc.
__global__ __launch_bounds__(256, 3) void wp_frag(
    const short* __restrict__ Afh, const short* __restrict__ Afl,
    const short* __restrict__ Bfh, const short* __restrict__ Bfl,
    float* __restrict__ C, const float* __restrict__ base,
    const float* __restrict__ colscale, int N, int K) {
  __shared__ short lds[24576];  // 48 KiB
  int bx = blockIdx.x, by = blockIdx.y;
  xcd_swizzle(bx, by, gridDim.x, gridDim.y);
  int m0 = bx * 64, n0 = by * 128;
  floatx16 acc[1][2] = {};
  gemm_frag_core<64, 128>(Afh, Afl, Bfh, Bfl, m0, n0, K, lds, acc);
  int lane = threadIdx.x & 63, wv = threadIdx.x >> 6;
  int wm = (wv >> 1) * 32, wn = (wv & 1) * 64;
  int cl = lane & 31, g2 = lane >> 5;
#pragma unroll
  for (int j = 0; j < 2; ++j) {
    int col = n0 + wn + 32 * j + cl;
    floatx16 f = acc[0][j];
    float cs = colscale ? colscale[col] : 1.f;
#pragma unroll
    for (int r = 0; r < 16; ++r) {
      int row = m0 + wm + (r & 3) + 8 * (r >> 2) + 4 * g2;
      size_t idx = (size_t)row * N + col;
      float v = f[r] * cs;
      if (base) v += base[idx];
      C[idx] = v;
    }
  }
}

// Fused q,k,v projection + head-RMS + RoPE (+q_gain):
// grid (NTOK/64, 12). by<8 -> q, 8-9 -> k, 10-11 -> v (+vemb).
// Each wave's output tile (32 rows x 64 cols) is EXACTLY ONE head:
//   head-RMS = 32-lane shfl_xor reduce (lanes sharing g2 hold one row's
//   64 cols, 2/lane); RoPE pair (d, d+32) is lane-local (frag j=0 <-> j=1).
// kb is written post-rope, so kvprep/attn are unchanged.
// ---------------------------------------------------------------------------
__global__ __launch_bounds__(256, 3) void qkv_frag(
    const short* __restrict__ xnh, const short* __restrict__ xnl,
    const short* __restrict__ wqh, const short* __restrict__ wql,
    const short* __restrict__ wkh, const short* __restrict__ wkl,
    const short* __restrict__ wvh, const short* __restrict__ wvl,
    float* __restrict__ qb, float* __restrict__ kb, float* __restrict__ vb,
    const float* __restrict__ vemb, const float* __restrict__ q_gain, int K) {
  __shared__ short lds[24576];  // 48 KiB
  int bx = blockIdx.x, by = blockIdx.y;
  xcd_swizzle(bx, by, gridDim.x, gridDim.y);
  const short *Bh, *Bl;
  float* C;
  const float* base = nullptr;
  int n0, ldn;
  if (by < 8) {
    Bh = wqh; Bl = wql; C = qb; n0 = by * 128; ldn = Dc;
  } else if (by < 10) {
    Bh = wkh; Bl = wkl; C = kb; n0 = (by - 8) * 128; ldn = KVDc;
  } else {
    Bh = wvh; Bl = wvl; C = vb; base = vemb; n0 = (by - 10) * 128; ldn = KVDc;
  }
  int m0 = bx * 64;
  floatx16 acc[1][2] = {};
  gemm_frag_core<64, 128>(xnh, xnl, Bh, Bl, m0, n0, K, lds, acc);
  int lane = threadIdx.x & 63, wv = threadIdx.x >> 6;
  int wm = (wv >> 1) * 32, wn = (wv & 1) * 64;
  int cl = lane & 31, g2 = lane >> 5;

  floatx16 f0 = acc[0][0], f1 = acc[0][1];
  if (by < 10) {
    // head-RMS + RoPE (+gain for q). Wave tile = one full head (64 cols).
    float gain = (by < 8) ? q_gain[by * 2 + (wv & 1)] : 1.f;
    float inv = expf(-(float)(2 * cl) * (9.210340372f / 64.f));
#pragma unroll
    for (int r = 0; r < 16; ++r) {
      float a0 = f0[r], a1 = f1[r];
      float ss = a0 * a0 + a1 * a1;
#pragma unroll
      for (int off = 1; off <= 16; off <<= 1) ss += __shfl_xor(ss, off);
      float rn = rsqrtf(ss / 64.f + 1e-6f);
      a0 *= rn;
      a1 *= rn;
      int row = m0 + wm + (r & 3) + 8 * (r >> 2) + 4 * g2;
      float ang = (float)(row & (Tc - 1)) * inv;
      float cv = cosf(ang), sv = sinf(ang);
      f0[r] = (a0 * cv + a1 * sv) * gain;
      f1[r] = (a1 * cv - a0 * sv) * gain;
    }
  }
#pragma unroll
  for (int j = 0; j < 2; ++j) {
    int col = n0 + wn + 32 * j + cl;
    floatx16 f = j ? f1 : f0;
#pragma unroll
    for (int r = 0; r < 16; ++r) {
      int row = m0 + wm + (r & 3) + 8 * (r >> 2) + 4 * g2;
      size_t idx = (size_t)row * ldn + col;
      float v = f[r];
      if (base) v += base[idx];
      C[idx] = v;
    }
  }
}

// Wfc GEMM: 128x128, act=1, writes h in FRAG-ORDER planes via LDS bounce.
__global__ __launch_bounds__(256, 2) void fc_frag(
    const short* __restrict__ Afh, const short* __restrict__ Afl,
    const short* __restrict__ Bfh, const short* __restrict__ Bfl,
    short* __restrict__ Chf, short* __restrict__ Clf, int N, int K,
    int K16out) {
  __shared__ short lds[32768];  // 64 KiB (reused for epilogue bounce)
  int bx = blockIdx.x, by = blockIdx.y;
  xcd_swizzle(bx, by, gridDim.x, gridDim.y);
  int m0 = bx * 128, n0 = by * 128;
  floatx16 acc[2][2] = {};
  gemm_frag_core<128, 128>(Afh, Afl, Bfh, Bfl, m0, n0, K, lds, acc);
  int tid = threadIdx.x;
  int lane = tid & 63, wv = tid >> 6;
  int wm = (wv >> 1) * 64, wn = (wv & 1) * 64;
  int cl = lane & 31, g2 = lane >> 5;
  __syncthreads();  // LDS free; begin frag-bounce
#pragma unroll
  for (int i = 0; i < 2; ++i)
#pragma unroll
    for (int j = 0; j < 2; ++j) {
      floatx16 f = acc[i][j];
#pragma unroll
      for (int r = 0; r < 16; ++r) {
        int rowl = wm + 32 * i + (r & 3) + 8 * (r >> 2) + 4 * g2;  // 0..127
        int coll = wn + 32 * j + cl;                                // 0..127
        float v = f[r];
        float hx = (v >= 0.f) ? v : 0.5f * v;
        v = hx * hx;
        short hb = f2bf(v);
        short lb = f2bf(v - bf2f(hb));
        int sub = (rowl >> 5) * 8 + (coll >> 4);
        int lanev = (rowl & 31) + 32 * ((coll >> 3) & 1);
        int off = sub * 512 + lanev * 8 + (coll & 7);
        lds[off] = hb;
        lds[16384 + off] = lb;
      }
    }
  __syncthreads();
  size_t gbase = ((size_t)(m0 >> 5) * K16out + (n0 >> 4)) * 512;
#pragma unroll
  for (int u = 0; u < 8; ++u) {
    int idx = u * 2048 + tid * 8;
    int sub = idx >> 9, within = idx & 511;
    size_t gidx = gbase + ((size_t)(sub >> 3) * K16out + (sub & 7)) * 512 + within;
    *(short8*)(Chf + gidx) = *(const short8*)(lds + idx);
    *(short8*)(Clf + gidx) = *(const short8*)(lds + 16384 + idx);
  }
}

// ---------------------------------------------------------------------------
// K/V^T frag-order plane prep (unchanged).
// ---------------------------------------------------------------------------
__global__ __launch_bounds__(256) void kvprep_kernel(
    const float* __restrict__ kb, const float* __restrict__ vb,
    short* __restrict__ khG, short* __restrict__ klG,
    short* __restrict__ vthG, short* __restrict__ vtlG) {
  __shared__ float kf[64][65];
  __shared__ float vf[64][65];
  int kt = blockIdx.x, bh = blockIdx.y;
  int b = bh >> 2, hkv = bh & 3;
  int tid = threadIdx.x;
#pragma unroll
  for (int u = 0; u < 4; ++u) {
    int idx = tid + u * 256;
    int row = idx >> 4, c4 = idx & 15;
    size_t off = ((size_t)(b * Tc + kt * 64 + row)) * KVDc + hkv * 64 + c4 * 4;
    float4 k4 = *(const float4*)(kb + off);
    float4 v4 = *(const float4*)(vb + off);
    kf[row][c4 * 4 + 0] = k4.x; kf[row][c4 * 4 + 1] = k4.y;
    kf[row][c4 * 4 + 2] = k4.z; kf[row][c4 * 4 + 3] = k4.w;
    vf[row][c4 * 4 + 0] = v4.x; vf[row][c4 * 4 + 1] = v4.y;
    vf[row][c4 * 4 + 2] = v4.z; vf[row][c4 * 4 + 3] = v4.w;
  }
  __syncthreads();
  size_t gb = ((size_t)(bh * (Tc / 64) + kt)) * 4096;
#pragma unroll
  for (int u = 0; u < 2; ++u) {
    int unit = tid + u * 256;
    int s = unit >> 6, p = unit & 63;
    {
      int half = s >> 2, rg = s & 3;
      int row = rg * 16 + (p & 15);
      int d0 = half * 32 + (p >> 4) * 8;
      short8 h8, l8;
#pragma unroll
      for (int e = 0; e < 8; ++e) {
        float v = kf[row][d0 + e];
        short hb = f2bf(v);
        h8[e] = hb;
        l8[e] = f2bf(v - bf2f(hb));
      }
      *(short8*)(khG + gb + s * 512 + p * 8) = h8;
      *(short8*)(klG + gb + s * 512 + p * 8) = l8;
    }
    {
      int ks = s >> 2, jd = s & 3;
      int d = jd * 16 + (p & 15);
      int k0 = ks * 32 + (p >> 4) * 8;
      short8 h8, l8;
#pragma unroll
      for (int e = 0; e < 8; ++e) {
        float v = vf[k0 + e][d];
        short hb = f2bf(v);
        h8[e] = hb;
        l8[e] = f2bf(v - bf2f(hb));
      }
      *(short8*)(vthG + gb + s * 512 + p * 8) = h8;
      *(short8*)(vtlG + gb + s * 512 + p * 8) = l8;
    }
  }
}

// ---------------------------------------------------------------------------
// MFMA causal GQA flash attention + v-direction-removal epilogue.
// y output written directly in FRAG-ORDER planes (consumed by wp_frag).
// ---------------------------------------------------------------------------
__global__ __launch_bounds__(256) void attn_mfma(
    const float* __restrict__ qg_, const float* __restrict__ vg_,
    const short* __restrict__ khG, const short* __restrict__ klG,
    const short* __restrict__ vthG, const short* __restrict__ vtlG,
    short* __restrict__ yh_, short* __restrict__ yl_) {
  __shared__ short smem[24576];  // 48 KiB
  short* Khi  = smem;
  short* Klo  = smem + 4096;
  short* Vthi = smem + 8192;
  short* Vtlo = smem + 12288;

  int bh = blockIdx.x;
  int qt = (gridDim.y - 1) - blockIdx.y;
  int b = bh >> 2, hkv = bh & 3;
  int tid = threadIdx.x;
  int lane = tid & 63, wv = tid >> 6;
  int x = lane & 15, g = lane >> 4;
  int h = hkv * 4 + wv;
  int qbase = qt * 16;

  short* PAhi = smem + 16384 + wv * 1024;
  short* PAlo = smem + 20480 + wv * 1024;

  short8 qh[2], qlo[2];
#pragma unroll
  for (int ks = 0; ks < 2; ++ks) {
    int qrow = qbase + x;
    const float* qp =
        qg_ + ((size_t)(b * Tc + qrow)) * Dc + h * 64 + ks * 32 + g * 8;
    float4 f0 = *(const float4*)qp;
    float4 f1 = *(const float4*)(qp + 4);
    float fv[8] = {f0.x, f0.y, f0.z, f0.w, f1.x, f1.y, f1.z, f1.w};
#pragma unroll
    for (int e = 0; e < 8; ++e) {
      short hb = f2bf(fv[e]);
      qh[ks][e] = hb;
      qlo[ks][e] = f2bf(fv[e] - bf2f(hb));
    }
  }

  const short* planes[4] = {khG, klG, vthG, vtlG};
  const short* gplane = planes[wv] + ((size_t)bh * (Tc / 64)) * 4096 + lane * 8;
  short* lplane = smem + wv * 4096;

  floatx4 o[4] = {};
  float m_run = NEG_BIG, l_run = 0.f;

  int nkt = (qbase >> 6) + 1;
  for (int kt = 0; kt < nkt; ++kt) {
    const short* gs = gplane + (size_t)kt * 4096;
#pragma unroll
    for (int t = 0; t < 8; ++t) gll16(gs + t * 512, lplane + t * 512);
    __syncthreads();

    floatx4 st[4] = {};
#pragma unroll
    for (int ks = 0; ks < 2; ++ks) {
#pragma unroll
      for (int i = 0; i < 4; ++i) {
        short8 ka_h = *(const short8*)(Khi + ks * 2048 + i * 512 + lane * 8);
        short8 ka_l = *(const short8*)(Klo + ks * 2048 + i * 512 + lane * 8);
        st[i] = __builtin_amdgcn_mfma_f32_16x16x32_bf16(ka_h, qh[ks], st[i], 0, 0, 0);
        st[i] = __builtin_amdgcn_mfma_f32_16x16x32_bf16(ka_h, qlo[ks], st[i], 0, 0, 0);
        st[i] = __builtin_amdgcn_mfma_f32_16x16x32_bf16(ka_l, qh[ks], st[i], 0, 0, 0);
      }
    }

    float alv;
    {
      int qrow = qbase + x;
      float mx = NEG_BIG;
#pragma unroll
      for (int i = 0; i < 4; ++i) {
#pragma unroll
        for (int r = 0; r < 4; ++r) {
          int krow = kt * 64 + 16 * i + 4 * g + r;
          float s = st[i][r] * 0.125f;
          if (krow > qrow) s = NEG_BIG;
          st[i][r] = s;
          mx = fmaxf(mx, s);
        }
      }
      mx = fmaxf(mx, __shfl_xor(mx, 16));
      mx = fmaxf(mx, __shfl_xor(mx, 32));
      float m_new = fmaxf(m_run, mx);
      alv = __expf(m_run - m_new);
      float ts = 0.f;
#pragma unroll
      for (int i = 0; i < 4; ++i) {
#pragma unroll
        for (int r = 0; r < 4; ++r) {
          float p = __expf(st[i][r] - m_new);
          st[i][r] = p;
          ts += p;
        }
      }
      ts += __shfl_xor(ts, 16);
      ts += __shfl_xor(ts, 32);
      l_run = l_run * alv + ts;
      m_run = m_new;
    }

#pragma unroll
    for (int i = 0; i < 4; ++i) {
      short4v h4, l4;
#pragma unroll
      for (int r = 0; r < 4; ++r) {
        float p = st[i][r];
        short hb = f2bf(p);
        h4[r] = hb;
        l4[r] = f2bf(p - bf2f(hb));
      }
      int offp = (i >> 1) * 512 +
                 (x + (2 * (i & 1) + (g >> 1)) * 16) * 8 + 4 * (g & 1);
      *(short4v*)(PAhi + offp) = h4;
      *(short4v*)(PAlo + offp) = l4;
    }

#pragma unroll
    for (int r = 0; r < 4; ++r) {
      float a = __shfl(alv, 4 * g + r);
#pragma unroll
      for (int jd = 0; jd < 4; ++jd) o[jd][r] *= a;
    }
    __syncthreads();

#pragma unroll
    for (int ks = 0; ks < 2; ++ks) {
      short8 pa_h = *(const short8*)(PAhi + ks * 512 + lane * 8);
      short8 pa_l = *(const short8*)(PAlo + ks * 512 + lane * 8);
#pragma unroll
      for (int jd = 0; jd < 4; ++jd) {
        short8 vb_h = *(const short8*)(Vthi + ks * 2048 + jd * 512 + lane * 8);
        short8 vb_l = *(const short8*)(Vtlo + ks * 2048 + jd * 512 + lane * 8);
        o[jd] = __builtin_amdgcn_mfma_f32_16x16x32_bf16(pa_h, vb_h, o[jd], 0, 0, 0);
        o[jd] = __builtin_amdgcn_mfma_f32_16x16x32_bf16(pa_h, vb_l, o[jd], 0, 0, 0);
        o[jd] = __builtin_amdgcn_mfma_f32_16x16x32_bf16(pa_l, vb_h, o[jd], 0, 0, 0);
      }
    }
    __syncthreads();
  }

  // finalize: /l_run, remove v-component, store y in FRAG-ORDER planes.
#pragma unroll
  for (int r = 0; r < 4; ++r) {
    float lr = __shfl(l_run, 4 * g + r);
    float rcp = 1.f / lr;
    int qrow = qbase + 4 * g + r;
    const float* vr = vg_ + ((size_t)(b * Tc + qrow)) * KVDc + hkv * 64;
    float vv[4], oo[4];
    float pn = 0.f, pd = 0.f;
#pragma unroll
    for (int jd = 0; jd < 4; ++jd) {
      vv[jd] = vr[16 * jd + x];
      oo[jd] = o[jd][r] * rcp;
      pn += vv[jd] * vv[jd];
      pd += oo[jd] * vv[jd];
    }
#pragma unroll
    for (int off = 1; off <= 8; off <<= 1) {
      pn += __shfl_xor(pn, off);
      pd += __shfl_xor(pd, off);
    }
    float nrm = sqrtf(pn);
    float mxv = fmaxf(nrm, 1e-12f);
    float si = 1.f / mxv;
    float co = pd * si * si;
    int grow = b * Tc + qrow;
    size_t fb = ((size_t)(grow >> 5)) * 64 * 512 +
                ((size_t)(grow & 31) + 32 * (x >> 3)) * 8 + (x & 7);
#pragma unroll
    for (int jd = 0; jd < 4; ++jd) {
      float val = oo[jd] - co * vv[jd];
      short hb = f2bf(val);
      size_t off = fb + (size_t)(h * 4 + jd) * 512;
      yh_[off] = hb;
      yl_[off] = f2bf(val - bf2f(hb));
    }
  }
}

// ---------------------------------------------------------------------------
extern "C" void kernel_launch(void* const* d_in, const int* in_sizes, int n_in,
                              void* d_out, int out_size, void* d_ws,
                              size_t ws_size, hipStream_t stream) {
  const int* ids          = (const int*)d_in[0];
  const float* embed_w    = (const float*)d_in[1];
  const float* big_w      = (const float*)d_in[2];
  const float* big_proj   = (const float*)d_in[3];
  const float* big_scale  = (const float*)d_in[4];
  const float* smear_gate = (const float*)d_in[5];
  const float* ve_w       = (const float*)d_in[6];
  const float* ve_proj    = (const float*)d_in[7];
  const float* ve_scale   = (const float*)d_in[8];
  const float* Wq         = (const float*)d_in[9];
  const float* Wk         = (const float*)d_in[10];
  const float* Wv         = (const float*)d_in[11];
  const float* Wo         = (const float*)d_in[12];
  const float* q_gain     = (const float*)d_in[13];
  const float* attn_scale = (const float*)d_in[14];
  const float* mlp_scale  = (const float*)d_in[15];
  const float* resid_mix  = (const float*)d_in[16];
  const float* Wfc        = (const float*)d_in[17];
  const float* Wp         = (const float*)d_in[18];
  const float* head_w     = (const float*)d_in[19];
  float* out = (float*)d_out;

  // ---- workspace layout ----
  char* p = (char*)d_ws;
  float* x     = (float*)p; p += SZ_X * 4;
  float* x0    = (float*)p; p += SZ_X * 4;
  float* x_in  = (float*)p; p += SZ_X * 4;
  float* qb    = (float*)p; p += SZ_X * 4;
  float* kb    = (float*)p; p += SZ_KV * 4;
  float* vb    = (float*)p; p += SZ_KV * 4;
  float* vemb  = (float*)p; p += SZ_KV * 4;
  float* raw_x = (float*)p; p += SZ_X * 4;
  short* xnh = (short*)p; p += SZ_X * 2;   // frag-order
  short* xnl = (short*)p; p += SZ_X * 2;
  short* yh  = (short*)p; p += SZ_X * 2;   // frag-order
  short* yl  = (short*)p; p += SZ_X * 2;
  short* hh  = (short*)p; p += SZ_H * 2;   // frag-order
  short* hl  = (short*)p; p += SZ_H * 2;
  short* khG  = (short*)p; p += SZ_KVP * 2;
  short* klG  = (short*)p; p += SZ_KVP * 2;
  short* vthG = (short*)p; p += SZ_KVP * 2;
  short* vtlG = (short*)p; p += SZ_KVP * 2;
  short* wqh = (short*)p; p += W_Q * 2;
  short* wql = (short*)p; p += W_Q * 2;
  short* wkh = (short*)p; p += W_KV * 2;
  short* wkl = (short*)p; p += W_KV * 2;
  short* wvh = (short*)p; p += W_KV * 2;
  short* wvl = (short*)p; p += W_KV * 2;
  short* woh = (short*)p; p += W_Q * 2;
  short* wol = (short*)p; p += W_Q * 2;
  short* wfh = (short*)p; p += W_FC * 2;
  short* wfl = (short*)p; p += W_FC * 2;
  short* wph = (short*)p; p += W_FC * 2;
  short* wpl = (short*)p; p += W_FC * 2;
  short* hwh = (short*)p; p += W_HD * 2;
  short* hwl = (short*)p; p += W_HD * 2;

  // ---- weight conversion: BATCHED over all layers (7 launches total).
  auto wcf = [&](const float* s, short* h, short* l2, int N, int Npad, int K) {
    long n8 = (long)Npad * (K >> 3);
    int blocks = (int)((n8 + 255) / 256);
    wcvt_frag_kernel<<<blocks, 256, 0, stream>>>(s, h, l2, N, Npad, K);
  };
  wcf(Wq, wqh, wql, Lc * Dc, Lc * Dc, Dc);
  wcf(Wk, wkh, wkl, Lc * KVDc, Lc * KVDc, Dc);
  wcf(Wv, wvh, wvl, Lc * KVDc, Lc * KVDc, Dc);
  wcf(Wo, woh, wol, Lc * Dc, Lc * Dc, Dc);
  wcf(Wfc, wfh, wfl, Lc * MLPc, Lc * MLPc, Dc);
  wcf(Wp, wph, wpl, Lc * Dc, Lc * Dc, MLPc);
  wcf(head_w, hwh, hwl, Vc, VPAD, Dc);

  embed_kernel<<<NTOK, 256, 0, stream>>>(ids, embed_w, big_w, big_proj,
                                         big_scale, ve_w, ve_proj, ve_scale,
                                         raw_x, vemb);
  smear_kernel<<<(int)(SZ_X / 256), 256, 0, stream>>>(raw_x, smear_gate, x, x0);

  for (int l = 0; l < Lc; ++l) {
    const float* mix = resid_mix + (size_t)l * 2 * Dc;
    prelayer_kernel<<<NTOK, 256, 0, stream>>>(x, x0, mix, x_in, xnh, xnl);
    // fused q,k,v projections + head-RMS + RoPE (+q_gain)
    qkv_frag<<<dim3(NTOK / 64, 12), 256, 0, stream>>>(
        xnh, xnl, wqh + (size_t)l * Dc * Dc, wql + (size_t)l * Dc * Dc,
        wkh + (size_t)l * KVDc * Dc, wkl + (size_t)l * KVDc * Dc,
        wvh + (size_t)l * KVDc * Dc, wvl + (size_t)l * KVDc * Dc, qb, kb, vb,
        vemb, q_gain + (size_t)l * Hc, Dc);
    kvprep_kernel<<<dim3(Tc / 64, Bc * HKVc), 256, 0, stream>>>(
        kb, vb, khG, klG, vthG, vtlG);
    attn_mfma<<<dim3(Bc * HKVc, Tc / 16), 256, 0, stream>>>(
        qb, vb, khG, klG, vthG, vtlG, yh, yl);
    // out proj + residual: x = x_in + attn_scale * (y @ Wo.T)
    wp_frag<<<dim3(NTOK / 64, Dc / 128), 256, 0, stream>>>(
        yh, yl, woh + (size_t)l * Dc * Dc, wol + (size_t)l * Dc * Dc, x, x_in,
        attn_scale + (size_t)l * Dc, Dc, Dc);
    // MLP
    rms_split_kernel<<<NTOK, 256, 0, stream>>>(x, xnh, xnl);
    fc_frag<<<dim3(NTOK / 128, MLPc / 128), 256, 0, stream>>>(
        xnh, xnl, wfh + (size_t)l * MLPc * Dc, wfl + (size_t)l * MLPc * Dc, hh,
        hl, MLPc, Dc, MLPc >> 4);
    wp_frag<<<dim3(NTOK / 64, Dc / 128), 256, 0, stream>>>(
        hh, hl, wph + (size_t)l * Dc * MLPc, wpl + (size_t)l * Dc * MLPc, x, x,
        mlp_scale + (size_t)l * Dc, Dc, MLPc);
  }

  rms_split_kernel<<<NTOK, 256, 0, stream>>>(x, xnh, xnl);
  head_frag<<<dim3(NTOK / 128, VPAD / 128), 256, 0, stream>>>(
      xnh, xnl, hwh, hwl, out, Vc, Dc);
}

// Round 15
// 4078.181 us; speedup vs baseline: 1.0610x; 1.0225x over previous
//
#include <hip/hip_runtime.h>
#include <hip/hip_bf16.h>

// Problem constants (match reference)
constexpr int Bc   = 2;
constexpr int Tc   = 1024;
constexpr int Vc   = 50257;
constexpr int Lc   = 8;
constexpr int Dc   = 1024;
constexpr int Hc   = 16;
constexpr int HKVc = 4;
constexpr int HDc  = 64;     // D/H
constexpr int KVDc = 256;    // HKV*HD
constexpr int MLPc = 4096;   // 4*D
constexpr int BVc  = 65536;
constexpr int BDc  = 256;
constexpr int VEDc = 128;

constexpr int NTOK = Bc * Tc;          // 2048
constexpr long SZ_X  = (long)NTOK * Dc;    // 2,097,152
constexpr long SZ_KV = (long)NTOK * KVDc;  // 524,288
constexpr long SZ_H  = (long)NTOK * MLPc;  // 8,388,608

constexpr int  VPAD = 50432;                  // Vc padded to 256
constexpr long W_Q  = (long)Lc * Dc * Dc;     // 8,388,608
constexpr long W_KV = (long)Lc * KVDc * Dc;   // 2,097,152
constexpr long W_FC = (long)Lc * MLPc * Dc;   // 33,554,432
constexpr long W_HD = (long)VPAD * Dc;        // frag-order, padded
constexpr long SZ_KVP = (long)Bc * HKVc * (Tc / 64) * 4096;  // shorts/plane

#define NEG_BIG (-3.0e38f)

typedef __attribute__((ext_vector_type(8))) short short8;    // 8 bf16 (4 VGPRs)
typedef __attribute__((ext_vector_type(4))) short short4v;   // 4 bf16 (8 B)
typedef __attribute__((ext_vector_type(4))) float floatx4;   // 16x16 MFMA acc
typedef __attribute__((ext_vector_type(16))) float floatx16; // 32x32 MFMA acc

__device__ __forceinline__ float wave_sum(float v) {
#pragma unroll
  for (int off = 32; off >= 1; off >>= 1) v += __shfl_xor(v, off);
  return v;
}

// Bijective XCD-aware swizzle (m204 formula).
__device__ __forceinline__ void xcd_swizzle(int& bx, int& by, int nbx, int nby) {
  int n = nbx * nby;
  int lin = by * nbx + bx;
  int q = n >> 3, rm = n & 7;
  int xcd = lin & 7, idx = lin >> 3;
  int v = (xcd < rm) ? (xcd * (q + 1) + idx)
                     : (rm * (q + 1) + (xcd - rm) * q + idx);
  bx = v % nbx;
  by = v / nbx;
}

// async global->LDS, 16B per lane. LDS dest = wave-uniform base + lane*16.
__device__ __forceinline__ void gll16(const void* g, void* l) {
  __builtin_amdgcn_global_load_lds(
      (const __attribute__((address_space(1))) unsigned int*)g,
      (__attribute__((address_space(3))) unsigned int*)l, 16, 0, 0);
}

// ---------------------------------------------------------------------------
// bf16 split helpers: f = bf2f(hi) + bf2f(lo) + O(2^-17 * f)
// ---------------------------------------------------------------------------
__device__ __forceinline__ short f2bf(float f) {
  unsigned u = __float_as_uint(f);
  return (short)((u + 0x7fffu + ((u >> 16) & 1u)) >> 16);
}
__device__ __forceinline__ float bf2f(short h) {
  return __uint_as_float(((unsigned)(unsigned short)h) << 16);
}

// ---------------------------------------------------------------------------
// Weight conversion: fp32 row-major [N][K] -> frag-order hi/lo planes
//   layout [Npad/32][K/16][64 lanes][8 shorts]; lane = (r&31) + 32*(k8&1).
// Layer-contiguous: batched over all layers in ONE launch.
// ---------------------------------------------------------------------------
__global__ __launch_bounds__(256) void wcvt_frag_kernel(
    const float* __restrict__ src, short* __restrict__ hi,
    short* __restrict__ lo, int N, int Npad, int K) {
  long i = (long)blockIdx.x * 256 + threadIdx.x;
  int K8 = K >> 3;
  long n8 = (long)Npad * K8;
  if (i >= n8) return;
  int r = (int)(i / K8);
  int k8 = (int)(i % K8);
  float fv[8] = {};
  if (r < N) {
    const float* s = src + (size_t)r * K + k8 * 8;
    float4 f0 = *(const float4*)s;
    float4 f1 = *(const float4*)(s + 4);
    fv[0] = f0.x; fv[1] = f0.y; fv[2] = f0.z; fv[3] = f0.w;
    fv[4] = f1.x; fv[5] = f1.y; fv[6] = f1.z; fv[7] = f1.w;
  }
  short8 h8, l8;
#pragma unroll
  for (int e = 0; e < 8; ++e) {
    short hb = f2bf(fv[e]);
    h8[e] = hb;
    l8[e] = f2bf(fv[e] - bf2f(hb));
  }
  int rg = r >> 5, ksi = k8 >> 1;
  int lanev = (r & 31) + ((k8 & 1) << 5);
  size_t off = (((size_t)rg * (K >> 4) + ksi) * 64 + lanev) * 8;
  *(short8*)(hi + off) = h8;
  *(short8*)(lo + off) = l8;
}

// ---------------------------------------------------------------------------
// Embedding (unchanged)
// ---------------------------------------------------------------------------
__global__ __launch_bounds__(256) void embed_kernel(
    const int* __restrict__ ids, const float* __restrict__ embed_w,
    const float* __restrict__ big_w, const float* __restrict__ big_proj,
    const float* __restrict__ big_scale, const float* __restrict__ ve_w,
    const float* __restrict__ ve_proj, const float* __restrict__ ve_scale,
    float* __restrict__ raw_x, float* __restrict__ vemb) {
  int bt = blockIdx.x;
  int tid = threadIdx.x;
  int t = bt % Tc;
  int tok = ids[bt];

  const float* e = embed_w + (size_t)tok * Dc;
  float ev[4];
  float ss = 0.f;
#pragma unroll
  for (int i = 0; i < 4; ++i) {
    ev[i] = e[tid + i * 256];
    ss += ev[i] * ev[i];
  }
  __shared__ float red[4];
  __shared__ float brow[BDc];
  __shared__ float verow[VEDc];
  float wsum = wave_sum(ss);
  if ((tid & 63) == 0) red[tid >> 6] = wsum;

  int bg;
  if (t == 0) {
    bg = BVc - 1;
  } else {
    unsigned a = (unsigned)ids[bt];
    unsigned p = (unsigned)ids[bt - 1];
    bg = (int)(((36313u * a) ^ (27191u * p)) % 65535u);
  }
  brow[tid] = big_w[(size_t)bg * BDc + tid];
  if (tid < VEDc) verow[tid] = ve_w[(size_t)tok * VEDc + tid];
  __syncthreads();

  float tot = red[0] + red[1] + red[2] + red[3];
  float rn = rsqrtf(tot / (float)Dc + 1e-6f);
  float bs = big_scale[0];
#pragma unroll
  for (int i = 0; i < 4; ++i) {
    int d = tid + i * 256;
    const float* bp = big_proj + (size_t)d * BDc;
    float dot = 0.f;
    for (int c = 0; c < BDc; ++c) dot += brow[c] * bp[c];
    raw_x[(size_t)bt * Dc + d] = ev[i] * rn + dot * bs;
  }
  {
    float vs = ve_scale[0];
    int d = tid;
    const float* vp = ve_proj + (size_t)d * VEDc;
    float dot = 0.f;
    for (int c = 0; c < VEDc; ++c) dot += verow[c] * vp[c];
    vemb[(size_t)bt * KVDc + d] = dot * vs;
  }
}

// ---------------------------------------------------------------------------
// Smear (unchanged)
// ---------------------------------------------------------------------------
__global__ __launch_bounds__(256) void smear_kernel(
    const float* __restrict__ raw, const float* __restrict__ gate,
    float* __restrict__ x, float* __restrict__ x0) {
  long idx = (long)blockIdx.x * 256 + threadIdx.x;
  if (idx >= SZ_X) return;
  int d = (int)(idx & (Dc - 1));
  int t = (int)((idx / Dc) & (Tc - 1));
  float g = 1.f / (1.f + expf(-gate[d]));
  float cur = raw[idx];
  float prev = (t > 0) ? raw[idx - Dc] : 0.f;
  float val = (1.f - g) * cur + g * prev;
  x[idx] = val;
  x0[idx] = val;
}

// ---------------------------------------------------------------------------
// frag-order activation store: token bt, 4 consecutive elems at d0=4*tid.
// ---------------------------------------------------------------------------
__device__ __forceinline__ void store_frag4(short* __restrict__ ph,
                                            short* __restrict__ pl, int bt,
                                            int d0, int K16, const float* v) {
  short4v h4, l4;
#pragma unroll
  for (int e = 0; e < 4; ++e) {
    short hb = f2bf(v[e]);
    h4[e] = hb;
    l4[e] = f2bf(v[e] - bf2f(hb));
  }
  int lanev = (bt & 31) + 32 * ((d0 >> 3) & 1);
  size_t off = (((size_t)(bt >> 5) * K16 + (d0 >> 4)) * 64 + lanev) * 8 + (d0 & 7);
  *(short4v*)(ph + off) = h4;
  *(short4v*)(pl + off) = l4;
}

// ---------------------------------------------------------------------------
// Pre-layer: x_in = mix0*x + mix1*x0 ; xn frag planes = split(rms(x_in)).
// ---------------------------------------------------------------------------
__global__ __launch_bounds__(256) void prelayer_kernel(
    const float* __restrict__ x, const float* __restrict__ x0,
    const float* __restrict__ mix, float* __restrict__ x_in,
    short* __restrict__ xnh, short* __restrict__ xnl) {
  int bt = blockIdx.x;
  int tid = threadIdx.x;
  int d0 = tid * 4;
  const float* xr = x + (size_t)bt * Dc;
  const float* x0r = x0 + (size_t)bt * Dc;
  float4 xv = *(const float4*)(xr + d0);
  float4 x0v = *(const float4*)(x0r + d0);
  float4 m0 = *(const float4*)(mix + d0);
  float4 m1 = *(const float4*)(mix + Dc + d0);
  float vals[4] = {m0.x * xv.x + m1.x * x0v.x, m0.y * xv.y + m1.y * x0v.y,
                   m0.z * xv.z + m1.z * x0v.z, m0.w * xv.w + m1.w * x0v.w};
  float ss = vals[0] * vals[0] + vals[1] * vals[1] + vals[2] * vals[2] +
             vals[3] * vals[3];
  __shared__ float red[4];
  float wsum = wave_sum(ss);
  if ((tid & 63) == 0) red[tid >> 6] = wsum;
  __syncthreads();
  float tot = red[0] + red[1] + red[2] + red[3];
  float rn = rsqrtf(tot / (float)Dc + 1e-6f);
  *(float4*)(x_in + (size_t)bt * Dc + d0) =
      make_float4(vals[0], vals[1], vals[2], vals[3]);
  float vn[4] = {vals[0] * rn, vals[1] * rn, vals[2] * rn, vals[3] * rn};
  store_frag4(xnh, xnl, bt, d0, Dc >> 4, vn);
}

// ---------------------------------------------------------------------------
// RMS over D -> frag-order bf16 hi/lo planes. Block per token.
// ---------------------------------------------------------------------------
__global__ __launch_bounds__(256) void rms_split_kernel(
    const float* __restrict__ in, short* __restrict__ oh,
    short* __restrict__ ol) {
  int bt = blockIdx.x;
  int tid = threadIdx.x;
  int d0 = tid * 4;
  float4 v4 = *(const float4*)(in + (size_t)bt * Dc + d0);
  float v[4] = {v4.x, v4.y, v4.z, v4.w};
  float ss = v[0] * v[0] + v[1] * v[1] + v[2] * v[2] + v[3] * v[3];
  __shared__ float red[4];
  float wsum = wave_sum(ss);
  if ((tid & 63) == 0) red[tid >> 6] = wsum;
  __syncthreads();
  float tot = red[0] + red[1] + red[2] + red[3];
  float rn = rsqrtf(tot / (float)Dc + 1e-6f);
  float vn[4] = {v[0] * rn, v[1] * rn, v[2] * rn, v[3] * rn};
  store_frag4(oh, ol, bt, d0, Dc >> 4, vn);
}

// ---------------------------------------------------------------------------
// Frag-order GEMM core (R9/R11 structure; best verified at ~50% MfmaUtil).
// A and B BOTH in frag-order global planes [R/32][K/16][64][8]; every
// global_load_lds is ONE contiguous 1KB packet. Counted-vmcnt double-buffered
// pipeline. >=2 blocks/CU give the 2-waves/SIMD overlap (R12 lesson: 1
// wave/SIMD serializes ds_read and MFMA and loses ~20%).
// ---------------------------------------------------------------------------
template <int BM, int BN>
__device__ __forceinline__ void gemm_frag_core(
    const short* __restrict__ Afh, const short* __restrict__ Afl,
    const short* __restrict__ Bfh, const short* __restrict__ Bfl, int m0,
    int n0, int K, short* lds, floatx16 (*acc)[BN / 64 > 0 ? BN / 64 : 1]) {
  constexpr int RGA = BM / 32;
  constexpr int RGB = BN / 32;
  constexpr int SPW = RGA + RGB;        // gll16 per wave per tile
  constexpr int PLA = RGA * 1024;
  constexpr int PLB = RGB * 1024;
  constexpr int HB = 2 * (PLA + PLB);   // shorts per buffer
  constexpr int FI = (BM >= 64) ? BM / 64 : 1;
  constexpr int FJ = (BN >= 64) ? BN / 64 : 1;
  constexpr int WMD = (BM >= 64) ? BM / 2 : 32;  // wave-tile M stride
  constexpr int WND = (BN >= 64) ? BN / 2 : 32;  // wave-tile N stride

  int tid = threadIdx.x, lane = tid & 63, wv = tid >> 6;
  int K16 = K >> 4;

  const short* gsrc[SPW];
  int ldst[SPW];
#pragma unroll
  for (int t = 0; t < SPW; ++t) {
    int s = wv * SPW + t;
    const short* plane;
    int poff, rg, ks;
    size_t base;
    if (s < RGA * 4) {
      int p = s / (RGA * 2);
      int rem = s % (RGA * 2);
      rg = rem >> 1; ks = rem & 1;
      plane = p ? Afl : Afh;
      poff = p ? PLA : 0;
      base = (((size_t)(m0 >> 5) + rg) * K16 + ks) * 512;
    } else {
      int s2 = s - RGA * 4;
      int p = s2 / (RGB * 2);
      int rem = s2 % (RGB * 2);
      rg = rem >> 1; ks = rem & 1;
      plane = p ? Bfl : Bfh;
      poff = 2 * PLA + (p ? PLB : 0);
      base = (((size_t)(n0 >> 5) + rg) * K16 + ks) * 512;
    }
    gsrc[t] = plane + base + lane * 8;
    ldst[t] = poff + (rg * 2 + ks) * 512;
  }

  int wm = (wv >> 1) * WMD, wn = (wv & 1) * WND;

  // prologue: tile 0 -> buf0, tile 1 -> buf1 (K >= 64 everywhere here)
#pragma unroll
  for (int t = 0; t < SPW; ++t) gll16(gsrc[t], lds + ldst[t]);
#pragma unroll
  for (int t = 0; t < SPW; ++t) gsrc[t] += 1024;
#pragma unroll
  for (int t = 0; t < SPW; ++t) gll16(gsrc[t], lds + HB + ldst[t]);
#pragma unroll
  for (int t = 0; t < SPW; ++t) gsrc[t] += 1024;

  int cur = 0;
  for (int k0 = 0; k0 < K; k0 += 32) {
    if (k0 + 32 < K) {
      if constexpr (SPW == 8) {
        asm volatile("s_waitcnt vmcnt(8)" ::: "memory");
      } else if constexpr (SPW == 6) {
        asm volatile("s_waitcnt vmcnt(6)" ::: "memory");
      } else {
        asm volatile("s_waitcnt vmcnt(4)" ::: "memory");
      }
    } else {
      asm volatile("s_waitcnt vmcnt(0)" ::: "memory");
    }
    __builtin_amdgcn_s_barrier();
    __builtin_amdgcn_sched_barrier(0);

    const short* As_h = lds + cur * HB;
    const short* As_l = As_h + PLA;
    const short* Bs_h = As_h + 2 * PLA;
    const short* Bs_l = Bs_h + PLB;
    short8 ah[2][FI], alx[2][FI], bhx[2][FJ], blx[2][FJ];
#pragma unroll
    for (int ks = 0; ks < 2; ++ks) {
#pragma unroll
      for (int i = 0; i < FI; ++i) {
        int rg = (wm >> 5) + i;
        ah[ks][i]  = *(const short8*)(As_h + (rg * 2 + ks) * 512 + lane * 8);
        alx[ks][i] = *(const short8*)(As_l + (rg * 2 + ks) * 512 + lane * 8);
      }
#pragma unroll
      for (int j = 0; j < FJ; ++j) {
        int rg = (wn >> 5) + j;
        bhx[ks][j] = *(const short8*)(Bs_h + (rg * 2 + ks) * 512 + lane * 8);
        blx[ks][j] = *(const short8*)(Bs_l + (rg * 2 + ks) * 512 + lane * 8);
      }
    }
    asm volatile("s_waitcnt lgkmcnt(0)" ::: "memory");
    __builtin_amdgcn_sched_barrier(0);
    __builtin_amdgcn_s_barrier();  // all waves done reading buf[cur]

    if (k0 + 64 < K) {  // stage tile k+2 into freed buffer
#pragma unroll
      for (int t = 0; t < SPW; ++t) gll16(gsrc[t], lds + cur * HB + ldst[t]);
#pragma unroll
      for (int t = 0; t < SPW; ++t) gsrc[t] += 1024;
    }
    __builtin_amdgcn_sched_barrier(0);

    __builtin_amdgcn_s_setprio(1);
#pragma unroll
    for (int ks = 0; ks < 2; ++ks) {
#pragma unroll
      for (int i = 0; i < FI; ++i)
#pragma unroll
        for (int j = 0; j < FJ; ++j)
          acc[i][j] = __builtin_amdgcn_mfma_f32_32x32x16_bf16(ah[ks][i], bhx[ks][j], acc[i][j], 0, 0, 0);
#pragma unroll
      for (int i = 0; i < FI; ++i)
#pragma unroll
        for (int j = 0; j < FJ; ++j)
          acc[i][j] = __builtin_amdgcn_mfma_f32_32x32x16_bf16(ah[ks][i], blx[ks][j], acc[i][j], 0, 0, 0);
#pragma unroll
      for (int i = 0; i < FI; ++i)
#pragma unroll
        for (int j = 0; j < FJ; ++j)
          acc[i][j] = __builtin_amdgcn_mfma_f32_32x32x16_bf16(alx[ks][i], bhx[ks][j], acc[i][j], 0, 0, 0);
    }
    __builtin_amdgcn_s_setprio(0);
    cur ^= 1;
  }
}

// head GEMM: 128x128, fp32 C with column guard.
__global__ __launch_bounds__(256, 2) void head_frag(
    const short* __restrict__ Afh, const short* __restrict__ Afl,
    const short* __restrict__ Bfh, const short* __restrict__ Bfl,
    float* __restrict__ C, int N, int K) {
  __shared__ short lds[32768];  // 64 KiB
  int bx = blockIdx.x, by = blockIdx.y;
  xcd_swizzle(bx, by, gridDim.x, gridDim.y);
  int m0 = bx * 128, n0 = by * 128;
  floatx16 acc[2][2] = {};
  gemm_frag_core<128, 128>(Afh, Afl, Bfh, Bfl, m0, n0, K, lds, acc);
  int lane = threadIdx.x & 63, wv = threadIdx.x >> 6;
  int wm = (wv >> 1) * 64, wn = (wv & 1) * 64;
  int cl = lane & 31, g2 = lane >> 5;
#pragma unroll
  for (int i = 0; i < 2; ++i)
#pragma unroll
    for (int j = 0; j < 2; ++j) {
      int col = n0 + wn + 32 * j + cl;
      if (col >= N) continue;
      floatx16 f = acc[i][j];
#pragma unroll
      for (int r = 0; r < 16; ++r) {
        int row = m0 + wm + 32 * i + (r & 3) + 8 * (r >> 2) + 4 * g2;
        C[(size_t)row * N + col] = f[r];
      }
    }
}

// Wo/Wp GEMM: 64x64 tile (512 blocks -> 2 blocks/CU: R12's 2-waves/SIMD
// overlap), fp32 C = base + colscale * acc. Numerics identical to 64x128
// (same per-output K order; tile size only repartitions outputs).
__global__ __launch_bounds__(256, 4) void wp64_frag(
    const short* __restrict__ Afh, const short* __restrict__ Afl,
    const short* __restrict__ Bfh, const short* __restrict__ Bfl,
    float* __restrict__ C, const float* __restrict__ base,
    const float* __restrict__ colscale, int N, int K) {
  __shared__ short lds[16384];  // 32 KiB (2 buffers x 16 KB)
  int bx = blockIdx.x, by = blockIdx.y;
  xcd_swizzle(bx, by, gridDim.x, gridDim.y);
  int m0 = bx * 64, n0 = by * 64;
  floatx16 acc[1][1] = {};
  gemm_frag_core<64, 64>(Afh, Afl, Bfh, Bfl, m0, n0, K, lds, acc);
  int lane = threadIdx.x & 63, wv = threadIdx.x >> 6;
  int wm = (wv >> 1) * 32, wn = (wv & 1) * 32;
  int cl = lane & 31, g2 = lane >> 5;
  int col = n0 + wn + cl;
  floatx16 f = acc[0][0];
  float cs = colscale ? colscale[col] : 1.f;
#pragma unroll
  for (int r = 0; r < 16; ++r) {
    int row = m0 + wm + (r & 3) + 8 * (r >> 2) + 4 * g2;
    size_t idx = (size_t)row * N + col;
    float v = f[r] * cs;
    if (base) v += base[idx];
    C[idx] = v;
  }
}

// Fused q,k,v projection + head-RMS + RoPE (+q_gain):
// grid (NTOK/64, 12). by<8 -> q, 8-9 -> k, 10-11 -> v (+vemb).
// Each wave's output tile (32 rows x 64 cols) is EXACTLY ONE head:
//   head-RMS = 32-lane shfl_xor reduce; RoPE pair (d, d+32) is lane-local
//   (frag j=0 <-> j=1). kb written post-rope; kvprep/attn unchanged.
// ---------------------------------------------------------------------------
__global__ __launch_bounds__(256, 3) void qkv_frag(
    const short* __restrict__ xnh, const short* __restrict__ xnl,
    const short* __restrict__ wqh, const short* __restrict__ wql,
    const short* __restrict__ wkh, const short* __restrict__ wkl,
    const short* __restrict__ wvh, const short* __restrict__ wvl,
    float* __restrict__ qb, float* __restrict__ kb, float* __restrict__ vb,
    const float* __restrict__ vemb, const float* __restrict__ q_gain, int K) {
  __shared__ short lds[24576];  // 48 KiB
  int bx = blockIdx.x, by = blockIdx.y;
  xcd_swizzle(bx, by, gridDim.x, gridDim.y);
  const short *Bh, *Bl;
  float* C;
  const float* base = nullptr;
  int n0, ldn;
  if (by < 8) {
    Bh = wqh; Bl = wql; C = qb; n0 = by * 128; ldn = Dc;
  } else if (by < 10) {
    Bh = wkh; Bl = wkl; C = kb; n0 = (by - 8) * 128; ldn = KVDc;
  } else {
    Bh = wvh; Bl = wvl; C = vb; base = vemb; n0 = (by - 10) * 128; ldn = KVDc;
  }
  int m0 = bx * 64;
  floatx16 acc[1][2] = {};
  gemm_frag_core<64, 128>(xnh, xnl, Bh, Bl, m0, n0, K, lds, acc);
  int lane = threadIdx.x & 63, wv = threadIdx.x >> 6;
  int wm = (wv >> 1) * 32, wn = (wv & 1) * 64;
  int cl = lane & 31, g2 = lane >> 5;

  floatx16 f0 = acc[0][0], f1 = acc[0][1];
  if (by < 10) {
    // head-RMS + RoPE (+gain for q). Wave tile = one full head (64 cols).
    float gain = (by < 8) ? q_gain[by * 2 + (wv & 1)] : 1.f;
    float inv = expf(-(float)(2 * cl) * (9.210340372f / 64.f));
#pragma unroll
    for (int r = 0; r < 16; ++r) {
      float a0 = f0[r], a1 = f1[r];
      float ss = a0 * a0 + a1 * a1;
#pragma unroll
      for (int off = 1; off <= 16; off <<= 1) ss += __shfl_xor(ss, off);
      float rn = rsqrtf(ss / 64.f + 1e-6f);
      a0 *= rn;
      a1 *= rn;
      int row = m0 + wm + (r & 3) + 8 * (r >> 2) + 4 * g2;
      float ang = (float)(row & (Tc - 1)) * inv;
      float cv = cosf(ang), sv = sinf(ang);
      f0[r] = (a0 * cv + a1 * sv) * gain;
      f1[r] = (a1 * cv - a0 * sv) * gain;
    }
  }
#pragma unroll
  for (int j = 0; j < 2; ++j) {
    int col = n0 + wn + 32 * j + cl;
    floatx16 f = j ? f1 : f0;
#pragma unroll
    for (int r = 0; r < 16; ++r) {
      int row = m0 + wm + (r & 3) + 8 * (r >> 2) + 4 * g2;
      size_t idx = (size_t)row * ldn + col;
      float v = f[r];
      if (base) v += base[idx];
      C[idx] = v;
    }
  }
}

// Wfc GEMM: 128x128, act=1, writes h in FRAG-ORDER planes via LDS bounce.
__global__ __launch_bounds__(256, 2) void fc_frag(
    const short* __restrict__ Afh, const short* __restrict__ Afl,
    const short* __restrict__ Bfh, const short* __restrict__ Bfl,
    short* __restrict__ Chf, short* __restrict__ Clf, int N, int K,
    int K16out) {
  __shared__ short lds[32768];  // 64 KiB (reused for epilogue bounce)
  int bx = blockIdx.x, by = blockIdx.y;
  xcd_swizzle(bx, by, gridDim.x, gridDim.y);
  int m0 = bx * 128, n0 = by * 128;
  floatx16 acc[2][2] = {};
  gemm_frag_core<128, 128>(Afh, Afl, Bfh, Bfl, m0, n0, K, lds, acc);
  int tid = threadIdx.x;
  int lane = tid & 63, wv = tid >> 6;
  int wm = (wv >> 1) * 64, wn = (wv & 1) * 64;
  int cl = lane & 31, g2 = lane >> 5;
  __syncthreads();  // LDS free; begin frag-bounce
#pragma unroll
  for (int i = 0; i < 2; ++i)
#pragma unroll
    for (int j = 0; j < 2; ++j) {
      floatx16 f = acc[i][j];
#pragma unroll
      for (int r = 0; r < 16; ++r) {
        int rowl = wm + 32 * i + (r & 3) + 8 * (r >> 2) + 4 * g2;  // 0..127
        int coll = wn + 32 * j + cl;                                // 0..127
        float v = f[r];
        float hx = (v >= 0.f) ? v : 0.5f * v;
        v = hx * hx;
        short hb = f2bf(v);
        short lb = f2bf(v - bf2f(hb));
        int sub = (rowl >> 5) * 8 + (coll >> 4);
        int lanev = (rowl & 31) + 32 * ((coll >> 3) & 1);
        int off = sub * 512 + lanev * 8 + (coll & 7);
        lds[off] = hb;
        lds[16384 + off] = lb;
      }
    }
  __syncthreads();
  size_t gbase = ((size_t)(m0 >> 5) * K16out + (n0 >> 4)) * 512;
#pragma unroll
  for (int u = 0; u < 8; ++u) {
    int idx = u * 2048 + tid * 8;
    int sub = idx >> 9, within = idx & 511;
    size_t gidx = gbase + ((size_t)(sub >> 3) * K16out + (sub & 7)) * 512 + within;
    *(short8*)(Chf + gidx) = *(const short8*)(lds + idx);
    *(short8*)(Clf + gidx) = *(const short8*)(lds + 16384 + idx);
  }
}

// ---------------------------------------------------------------------------
// K/V^T frag-order plane prep (unchanged).
// ---------------------------------------------------------------------------
__global__ __launch_bounds__(256) void kvprep_kernel(
    const float* __restrict__ kb, const float* __restrict__ vb,
    short* __restrict__ khG, short* __restrict__ klG,
    short* __restrict__ vthG, short* __restrict__ vtlG) {
  __shared__ float kf[64][65];
  __shared__ float vf[64][65];
  int kt = blockIdx.x, bh = blockIdx.y;
  int b = bh >> 2, hkv = bh & 3;
  int tid = threadIdx.x;
#pragma unroll
  for (int u = 0; u < 4; ++u) {
    int idx = tid + u * 256;
    int row = idx >> 4, c4 = idx & 15;
    size_t off = ((size_t)(b * Tc + kt * 64 + row)) * KVDc + hkv * 64 + c4 * 4;
    float4 k4 = *(const float4*)(kb + off);
    float4 v4 = *(const float4*)(vb + off);
    kf[row][c4 * 4 + 0] = k4.x; kf[row][c4 * 4 + 1] = k4.y;
    kf[row][c4 * 4 + 2] = k4.z; kf[row][c4 * 4 + 3] = k4.w;
    vf[row][c4 * 4 + 0] = v4.x; vf[row][c4 * 4 + 1] = v4.y;
    vf[row][c4 * 4 + 2] = v4.z; vf[row][c4 * 4 + 3] = v4.w;
  }
  __syncthreads();
  size_t gb = ((size_t)(bh * (Tc / 64) + kt)) * 4096;
#pragma unroll
  for (int u = 0; u < 2; ++u) {
    int unit = tid + u * 256;
    int s = unit >> 6, p = unit & 63;
    {
      int half = s >> 2, rg = s & 3;
      int row = rg * 16 + (p & 15);
      int d0 = half * 32 + (p >> 4) * 8;
      short8 h8, l8;
#pragma unroll
      for (int e = 0; e < 8; ++e) {
        float v = kf[row][d0 + e];
        short hb = f2bf(v);
        h8[e] = hb;
        l8[e] = f2bf(v - bf2f(hb));
      }
      *(short8*)(khG + gb + s * 512 + p * 8) = h8;
      *(short8*)(klG + gb + s * 512 + p * 8) = l8;
    }
    {
      int ks = s >> 2, jd = s & 3;
      int d = jd * 16 + (p & 15);
      int k0 = ks * 32 + (p >> 4) * 8;
      short8 h8, l8;
#pragma unroll
      for (int e = 0; e < 8; ++e) {
        float v = vf[k0 + e][d];
        short hb = f2bf(v);
        h8[e] = hb;
        l8[e] = f2bf(v - bf2f(hb));
      }
      *(short8*)(vthG + gb + s * 512 + p * 8) = h8;
      *(short8*)(vtlG + gb + s * 512 + p * 8) = l8;
    }
  }
}

// ---------------------------------------------------------------------------
// MFMA causal GQA flash attention + v-direction-removal epilogue.
// y output written directly in FRAG-ORDER planes (consumed by wp64_frag).
// ---------------------------------------------------------------------------
__global__ __launch_bounds__(256) void attn_mfma(
    const float* __restrict__ qg_, const float* __restrict__ vg_,
    const short* __restrict__ khG, const short* __restrict__ klG,
    const short* __restrict__ vthG, const short* __restrict__ vtlG,
    short* __restrict__ yh_, short* __restrict__ yl_) {
  __shared__ short smem[24576];  // 48 KiB
  short* Khi  = smem;
  short* Klo  = smem + 4096;
  short* Vthi = smem + 8192;
  short* Vtlo = smem + 12288;

  int bh = blockIdx.x;
  int qt = (gridDim.y - 1) - blockIdx.y;
  int b = bh >> 2, hkv = bh & 3;
  int tid = threadIdx.x;
  int lane = tid & 63, wv = tid >> 6;
  int x = lane & 15, g = lane >> 4;
  int h = hkv * 4 + wv;
  int qbase = qt * 16;

  short* PAhi = smem + 16384 + wv * 1024;
  short* PAlo = smem + 20480 + wv * 1024;

  short8 qh[2], qlo[2];
#pragma unroll
  for (int ks = 0; ks < 2; ++ks) {
    int qrow = qbase + x;
    const float* qp =
        qg_ + ((size_t)(b * Tc + qrow)) * Dc + h * 64 + ks * 32 + g * 8;
    float4 f0 = *(const float4*)qp;
    float4 f1 = *(const float4*)(qp + 4);
    float fv[8] = {f0.x, f0.y, f0.z, f0.w, f1.x, f1.y, f1.z, f1.w};
#pragma unroll
    for (int e = 0; e < 8; ++e) {
      short hb = f2bf(fv[e]);
      qh[ks][e] = hb;
      qlo[ks][e] = f2bf(fv[e] - bf2f(hb));
    }
  }

  const short* planes[4] = {khG, klG, vthG, vtlG};
  const short* gplane = planes[wv] + ((size_t)bh * (Tc / 64)) * 4096 + lane * 8;
  short* lplane = smem + wv * 4096;

  floatx4 o[4] = {};
  float m_run = NEG_BIG, l_run = 0.f;

  int nkt = (qbase >> 6) + 1;
  for (int kt = 0; kt < nkt; ++kt) {
    const short* gs = gplane + (size_t)kt * 4096;
#pragma unroll
    for (int t = 0; t < 8; ++t) gll16(gs + t * 512, lplane + t * 512);
    __syncthreads();

    floatx4 st[4] = {};
#pragma unroll
    for (int ks = 0; ks < 2; ++ks) {
#pragma unroll
      for (int i = 0; i < 4; ++i) {
        short8 ka_h = *(const short8*)(Khi + ks * 2048 + i * 512 + lane * 8);
        short8 ka_l = *(const short8*)(Klo + ks * 2048 + i * 512 + lane * 8);
        st[i] = __builtin_amdgcn_mfma_f32_16x16x32_bf16(ka_h, qh[ks], st[i], 0, 0, 0);
        st[i] = __builtin_amdgcn_mfma_f32_16x16x32_bf16(ka_h, qlo[ks], st[i], 0, 0, 0);
        st[i] = __builtin_amdgcn_mfma_f32_16x16x32_bf16(ka_l, qh[ks], st[i], 0, 0, 0);
      }
    }

    float alv;
    {
      int qrow = qbase + x;
      float mx = NEG_BIG;
#pragma unroll
      for (int i = 0; i < 4; ++i) {
#pragma unroll
        for (int r = 0; r < 4; ++r) {
          int krow = kt * 64 + 16 * i + 4 * g + r;
          float s = st[i][r] * 0.125f;
          if (krow > qrow) s = NEG_BIG;
          st[i][r] = s;
          mx = fmaxf(mx, s);
        }
      }
      mx = fmaxf(mx, __shfl_xor(mx, 16));
      mx = fmaxf(mx, __shfl_xor(mx, 32));
      float m_new = fmaxf(m_run, mx);
      alv = __expf(m_run - m_new);
      float ts = 0.f;
#pragma unroll
      for (int i = 0; i < 4; ++i) {
#pragma unroll
        for (int r = 0; r < 4; ++r) {
          float p = __expf(st[i][r] - m_new);
          st[i][r] = p;
          ts += p;
        }
      }
      ts += __shfl_xor(ts, 16);
      ts += __shfl_xor(ts, 32);
      l_run = l_run * alv + ts;
      m_run = m_new;
    }

#pragma unroll
    for (int i = 0; i < 4; ++i) {
      short4v h4, l4;
#pragma unroll
      for (int r = 0; r < 4; ++r) {
        float p = st[i][r];
        short hb = f2bf(p);
        h4[r] = hb;
        l4[r] = f2bf(p - bf2f(hb));
      }
      int offp = (i >> 1) * 512 +
                 (x + (2 * (i & 1) + (g >> 1)) * 16) * 8 + 4 * (g & 1);
      *(short4v*)(PAhi + offp) = h4;
      *(short4v*)(PAlo + offp) = l4;
    }

#pragma unroll
    for (int r = 0; r < 4; ++r) {
      float a = __shfl(alv, 4 * g + r);
#pragma unroll
      for (int jd = 0; jd < 4; ++jd) o[jd][r] *= a;
    }
    __syncthreads();

#pragma unroll
    for (int ks = 0; ks < 2; ++ks) {
      short8 pa_h = *(const short8*)(PAhi + ks * 512 + lane * 8);
      short8 pa_l = *(const short8*)(PAlo + ks * 512 + lane * 8);
#pragma unroll
      for (int jd = 0; jd < 4; ++jd) {
        short8 vb_h = *(const short8*)(Vthi + ks * 2048 + jd * 512 + lane * 8);
        short8 vb_l = *(const short8*)(Vtlo + ks * 2048 + jd * 512 + lane * 8);
        o[jd] = __builtin_amdgcn_mfma_f32_16x16x32_bf16(pa_h, vb_h, o[jd], 0, 0, 0);
        o[jd] = __builtin_amdgcn_mfma_f32_16x16x32_bf16(pa_h, vb_l, o[jd], 0, 0, 0);
        o[jd] = __builtin_amdgcn_mfma_f32_16x16x32_bf16(pa_l, vb_h, o[jd], 0, 0, 0);
      }
    }
    __syncthreads();
  }

  // finalize: /l_run, remove v-component, store y in FRAG-ORDER planes.
#pragma unroll
  for (int r = 0; r < 4; ++r) {
    float lr = __shfl(l_run, 4 * g + r);
    float rcp = 1.f / lr;
    int qrow = qbase + 4 * g + r;
    const float* vr = vg_ + ((size_t)(b * Tc + qrow)) * KVDc + hkv * 64;
    float vv[4], oo[4];
    float pn = 0.f, pd = 0.f;
#pragma unroll
    for (int jd = 0; jd < 4; ++jd) {
      vv[jd] = vr[16 * jd + x];
      oo[jd] = o[jd][r] * rcp;
      pn += vv[jd] * vv[jd];
      pd += oo[jd] * vv[jd];
    }
#pragma unroll
    for (int off = 1; off <= 8; off <<= 1) {
      pn += __shfl_xor(pn, off);
      pd += __shfl_xor(pd, off);
    }
    float nrm = sqrtf(pn);
    float mxv = fmaxf(nrm, 1e-12f);
    float si = 1.f / mxv;
    float co = pd * si * si;
    int grow = b * Tc + qrow;
    size_t fb = ((size_t)(grow >> 5)) * 64 * 512 +
                ((size_t)(grow & 31) + 32 * (x >> 3)) * 8 + (x & 7);
#pragma unroll
    for (int jd = 0; jd < 4; ++jd) {
      float val = oo[jd] - co * vv[jd];
      short hb = f2bf(val);
      size_t off = fb + (size_t)(h * 4 + jd) * 512;
      yh_[off] = hb;
      yl_[off] = f2bf(val - bf2f(hb));
    }
  }
}

// ---------------------------------------------------------------------------
extern "C" void kernel_launch(void* const* d_in, const int* in_sizes, int n_in,
                              void* d_out, int out_size, void* d_ws,
                              size_t ws_size, hipStream_t stream) {
  const int* ids          = (const int*)d_in[0];
  const float* embed_w    = (const float*)d_in[1];
  const float* big_w      = (const float*)d_in[2];
  const float* big_proj   = (const float*)d_in[3];
  const float* big_scale  = (const float*)d_in[4];
  const float* smear_gate = (const float*)d_in[5];
  const float* ve_w       = (const float*)d_in[6];
  const float* ve_proj    = (const float*)d_in[7];
  const float* ve_scale   = (const float*)d_in[8];
  const float* Wq         = (const float*)d_in[9];
  const float* Wk         = (const float*)d_in[10];
  const float* Wv         = (const float*)d_in[11];
  const float* Wo         = (const float*)d_in[12];
  const float* q_gain     = (const float*)d_in[13];
  const float* attn_scale = (const float*)d_in[14];
  const float* mlp_scale  = (const float*)d_in[15];
  const float* resid_mix  = (const float*)d_in[16];
  const float* Wfc        = (const float*)d_in[17];
  const float* Wp         = (const float*)d_in[18];
  const float* head_w     = (const float*)d_in[19];
  float* out = (float*)d_out;

  // ---- workspace layout ----
  char* p = (char*)d_ws;
  float* x     = (float*)p; p += SZ_X * 4;
  float* x0    = (float*)p; p += SZ_X * 4;
  float* x_in  = (float*)p; p += SZ_X * 4;
  float* qb    = (float*)p; p += SZ_X * 4;
  float* kb    = (float*)p; p += SZ_KV * 4;
  float* vb    = (float*)p; p += SZ_KV * 4;
  float* vemb  = (float*)p; p += SZ_KV * 4;
  float* raw_x = (float*)p; p += SZ_X * 4;
  short* xnh = (short*)p; p += SZ_X * 2;   // frag-order
  short* xnl = (short*)p; p += SZ_X * 2;
  short* yh  = (short*)p; p += SZ_X * 2;   // frag-order
  short* yl  = (short*)p; p += SZ_X * 2;
  short* hh  = (short*)p; p += SZ_H * 2;   // frag-order
  short* hl  = (short*)p; p += SZ_H * 2;
  short* khG  = (short*)p; p += SZ_KVP * 2;
  short* klG  = (short*)p; p += SZ_KVP * 2;
  short* vthG = (short*)p; p += SZ_KVP * 2;
  short* vtlG = (short*)p; p += SZ_KVP * 2;
  short* wqh = (short*)p; p += W_Q * 2;
  short* wql = (short*)p; p += W_Q * 2;
  short* wkh = (short*)p; p += W_KV * 2;
  short* wkl = (short*)p; p += W_KV * 2;
  short* wvh = (short*)p; p += W_KV * 2;
  short* wvl = (short*)p; p += W_KV * 2;
  short* woh = (short*)p; p += W_Q * 2;
  short* wol = (short*)p; p += W_Q * 2;
  short* wfh = (short*)p; p += W_FC * 2;
  short* wfl = (short*)p; p += W_FC * 2;
  short* wph = (short*)p; p += W_FC * 2;
  short* wpl = (short*)p; p += W_FC * 2;
  short* hwh = (short*)p; p += W_HD * 2;
  short* hwl = (short*)p; p += W_HD * 2;

  // ---- weight conversion: BATCHED over all layers (7 launches total).
  auto wcf = [&](const float* s, short* h, short* l2, int N, int Npad, int K) {
    long n8 = (long)Npad * (K >> 3);
    int blocks = (int)((n8 + 255) / 256);
    wcvt_frag_kernel<<<blocks, 256, 0, stream>>>(s, h, l2, N, Npad, K);
  };
  wcf(Wq, wqh, wql, Lc * Dc, Lc * Dc, Dc);
  wcf(Wk, wkh, wkl, Lc * KVDc, Lc * KVDc, Dc);
  wcf(Wv, wvh, wvl, Lc * KVDc, Lc * KVDc, Dc);
  wcf(Wo, woh, wol, Lc * Dc, Lc * Dc, Dc);
  wcf(Wfc, wfh, wfl, Lc * MLPc, Lc * MLPc, Dc);
  wcf(Wp, wph, wpl, Lc * Dc, Lc * Dc, MLPc);
  wcf(head_w, hwh, hwl, Vc, VPAD, Dc);

  embed_kernel<<<NTOK, 256, 0, stream>>>(ids, embed_w, big_w, big_proj,
                                         big_scale, ve_w, ve_proj, ve_scale,
                                         raw_x, vemb);
  smear_kernel<<<(int)(SZ_X / 256), 256, 0, stream>>>(raw_x, smear_gate, x, x0);

  for (int l = 0; l < Lc; ++l) {
    const float* mix = resid_mix + (size_t)l * 2 * Dc;
    prelayer_kernel<<<NTOK, 256, 0, stream>>>(x, x0, mix, x_in, xnh, xnl);
    // fused q,k,v projections + head-RMS + RoPE (+q_gain)
    qkv_frag<<<dim3(NTOK / 64, 12), 256, 0, stream>>>(
        xnh, xnl, wqh + (size_t)l * Dc * Dc, wql + (size_t)l * Dc * Dc,
        wkh + (size_t)l * KVDc * Dc, wkl + (size_t)l * KVDc * Dc,
        wvh + (size_t)l * KVDc * Dc, wvl + (size_t)l * KVDc * Dc, qb, kb, vb,
        vemb, q_gain + (size_t)l * Hc, Dc);
    kvprep_kernel<<<dim3(Tc / 64, Bc * HKVc), 256, 0, stream>>>(
        kb, vb, khG, klG, vthG, vtlG);
    attn_mfma<<<dim3(Bc * HKVc, Tc / 16), 256, 0, stream>>>(
        qb, vb, khG, klG, vthG, vtlG, yh, yl);
    // out proj + residual: x = x_in + attn_scale * (y @ Wo.T)  (512 blocks)
    wp64_frag<<<dim3(NTOK / 64, Dc / 64), 256, 0, stream>>>(
        yh, yl, woh + (size_t)l * Dc * Dc, wol + (size_t)l * Dc * Dc, x, x_in,
        attn_scale + (size_t)l * Dc, Dc, Dc);
    // MLP
    rms_split_kernel<<<NTOK, 256, 0, stream>>>(x, xnh, xnl);
    fc_frag<<<dim3(NTOK / 128, MLPc / 128), 256, 0, stream>>>(
        xnh, xnl, wfh + (size_t)l * MLPc * Dc, wfl + (size_t)l * MLPc * Dc, hh,
        hl, MLPc, Dc, MLPc >> 4);
    wp64_frag<<<dim3(NTOK / 64, Dc / 64), 256, 0, stream>>>(
        hh, hl, wph + (size_t)l * Dc * MLPc, wpl + (size_t)l * Dc * MLPc, x, x,
        mlp_scale + (size_t)l * Dc, Dc, MLPc);
  }

  rms_split_kernel<<<NTOK, 256, 0, stream>>>(x, xnh, xnl);
  head_frag<<<dim3(NTOK / 128, VPAD / 128), 256, 0, stream>>>(
      xnh, xnl, hwh, hwl, out, Vc, Dc);
}